// Round 1
// 786.888 us; speedup vs baseline: 1.5896x; 1.5896x over previous
//
#include <hip/hip_runtime.h>
#include <hip/hip_bf16.h>

#define NN    9216      /* 96*96   */
#define MM    2304      /* 48*48   */
#define HW    36864     /* 192*192 */
#define SLABF 4718592   /* f32 per batch slab of output: 128*192*192 */
#define TEMPF 5.0f

/* d_out f32 offsets (scratch; lifetimes verified):
   x    [0        , 4718592)   dead after theta/phi convs
   y    [4718592  , 9437184)   dead after g conv
   th   [9437184  , 11796480)  dead after attn
   tp   [11796480 , 14155776)  pre-pool temp, dead after pools
   ph   [14155776 , 14745600)  dead after attn
   g    [14745600 , 15335424)  dead after attn
   omap [15335424 , 17694720)  attn out, read by oconv
   ofin : swizzled into plane-0..31 prefix of each batch slab (race-free k_up) */
#define OFF_X   0
#define OFF_Y   4718592
#define OFF_TH  9437184
#define OFF_TP  11796480
#define OFF_PH  14155776
#define OFF_G   14745600
#define OFF_OM  15335424

typedef unsigned short u16;
typedef unsigned int   u32;
typedef __attribute__((ext_vector_type(8))) short bf16x8;
typedef __attribute__((ext_vector_type(4))) float f32x4;

__device__ __forceinline__ u16 f2bf(float f){
  u32 u; __builtin_memcpy(&u,&f,4);
  u32 lsb = (u>>16)&1u; u += 0x7fffu + lsb;   /* RNE */
  return (u16)(u>>16);
}
__device__ __forceinline__ u32 pkbf(float a, float b){
  union { __hip_bfloat162 h; u32 u; } v;
  v.h = __float22bfloat162_rn(make_float2(a,b));
  return v.u;
}

/* ---- down conv k=2 s=2, 128->128, f32, LDS-tiled ----
   Old version: latency-bound (c-loop stride 147 KB, 4x XCD over-fetch).
   New: block = (b, i, jt): all 128 o x 48 output cols of row i.
   Stage 32 channels/chunk into LDS, double-buffered (24.6 KB x2 -> 3 blk/CU).
   LDS layout per chunk: xs[c][col][r] row-INTERLEAVED so each thread's
   2-row x 6-col patch is 12 contiguous floats = 3x ds_read_b128 (16B aligned,
   2-way bank aliasing only = free).
   Thread tile: 8 o x 3 j -> 96 FMA : 3 ds_b128 per channel (VALU-bound).
   T14 async-stage split: global loads for chunk+1 issued before the barrier,
   ds_writes after compute, so HBM latency hides under the FMA phase. */
__global__ __launch_bounds__(256) void k_down(const float* __restrict__ in,
    const float* __restrict__ w, const float* __restrict__ bias, float* __restrict__ out)
{
  __shared__ __align__(16) float xs[2][6144];   /* [32 c][96 col][2 r] interleaved */
  int blk = blockIdx.x;
  int jt = blk & 1;                  /* 2 col-tiles of 48 */
  int r1 = blk >> 1;
  int i  = r1 % 96; int b = r1 / 96;
  int t  = threadIdx.x;

  const float* src = in + (size_t)b*128*HW + (size_t)(2*i)*192 + jt*96;

  /* stage task split: 768 tasks/chunk = 3 per thread; idx -> (cl, q) */
  int cl[3], qq[3];
  #pragma unroll
  for (int k = 0; k < 3; k++) {
    int idx = t + k*256;
    cl[k] = idx / 24;                /* channel-in-chunk 0..31 */
    qq[k] = idx - cl[k]*24;          /* col-group of 4, 0..23  */
  }

  float4 va[3], vb[3];
  /* prologue: stage chunk 0 */
  #pragma unroll
  for (int k = 0; k < 3; k++) {
    const float* p = src + (size_t)cl[k]*HW + qq[k]*4;
    va[k] = *(const float4*)p;
    vb[k] = *(const float4*)(p + 192);
  }
  #pragma unroll
  for (int k = 0; k < 3; k++) {
    float* d = &xs[0][cl[k]*192 + qq[k]*8];
    *(float4*)d       = make_float4(va[k].x, vb[k].x, va[k].y, vb[k].y);
    *(float4*)(d + 4) = make_float4(va[k].z, vb[k].z, va[k].w, vb[k].w);
  }

  int og = t >> 4, jg = t & 15;      /* 16 og x 8 o ; 16 jg x 3 j */
  int o0 = og * 8;
  float acc[8][3];
  #pragma unroll
  for (int oo = 0; oo < 8; oo++)
    #pragma unroll
    for (int jj = 0; jj < 3; jj++) acc[oo][jj] = 0.f;

  const float* wbase = w + (size_t)o0*512;   /* w[o][c][4] */

  for (int ch = 0; ch < 4; ch++) {
    /* issue next chunk's global loads early (hide under compute) */
    if (ch < 3) {
      #pragma unroll
      for (int k = 0; k < 3; k++) {
        const float* p = src + (size_t)((ch+1)*32 + cl[k])*HW + qq[k]*4;
        va[k] = *(const float4*)p;
        vb[k] = *(const float4*)(p + 192);
      }
    }
    __syncthreads();                 /* chunk ch LDS writes visible */

    const float* xb = xs[ch & 1];
    const float* wc = wbase + (ch*32)*4;
    for (int c = 0; c < 32; c++) {
      const float* xp = xb + c*192 + jg*12;
      float4 xv0 = *(const float4*)(xp);
      float4 xv1 = *(const float4*)(xp + 4);
      float4 xv2 = *(const float4*)(xp + 8);
      const float* wp = wc + c*4;
      #pragma unroll
      for (int oo = 0; oo < 8; oo++) {
        float4 wv = *(const float4*)(wp + oo*512);
        acc[oo][0] += xv0.x*wv.x + xv0.z*wv.y + xv0.y*wv.z + xv0.w*wv.w;
        acc[oo][1] += xv1.x*wv.x + xv1.z*wv.y + xv1.y*wv.z + xv1.w*wv.w;
        acc[oo][2] += xv2.x*wv.x + xv2.z*wv.y + xv2.y*wv.z + xv2.w*wv.w;
      }
    }

    /* write next chunk into the other buffer, after compute (T14 split) */
    if (ch < 3) {
      #pragma unroll
      for (int k = 0; k < 3; k++) {
        float* d = &xs[(ch+1) & 1][cl[k]*192 + qq[k]*8];
        *(float4*)d       = make_float4(va[k].x, vb[k].x, va[k].y, vb[k].y);
        *(float4*)(d + 4) = make_float4(va[k].z, vb[k].z, va[k].w, vb[k].w);
      }
    }
  }

  /* epilogue: out[b][o][i][jt*48 + jg*3 + {0,1,2}] */
  #pragma unroll
  for (int oo = 0; oo < 8; oo++) {
    int o = o0 + oo;
    float bv = bias[o];
    float* op = out + ((size_t)(b*128 + o))*NN + i*96 + jt*48 + jg*3;
    op[0] = acc[oo][0] + bv;
    op[1] = acc[oo][1] + bv;
    op[2] = acc[oo][2] + bv;
  }
}

/* ---- 1x1 conv 128->64: out[b][cc][n] = sum_c W[cc][c]*X[b][c][n] ---- */
__global__ __launch_bounds__(256) void k_conv(const float* __restrict__ X,
    const float* __restrict__ WG, float* __restrict__ out)
{
  __shared__ __align__(16) float Xs[128*32];   /* [c][32 n] 16KB */
  __shared__ __align__(16) float wt[128*64];   /* [c][cc]   32KB */
  int b  = blockIdx.x / 288;
  int n0 = (blockIdx.x % 288) * 32;
  int t  = threadIdx.x;
  for (int idx = t; idx < 8192; idx += 256) {
    int c = idx >> 6, cc = idx & 63;
    wt[idx] = WG[cc*128 + c];
  }
  for (int idx = t; idx < 1024; idx += 256) {  /* 128 rows x 8 float4 */
    int c = idx >> 3, wq = idx & 7;
    ((float4*)Xs)[idx] = *(const float4*)&X[((size_t)(b*128 + c))*NN + n0 + wq*4];
  }
  __syncthreads();
  int n = t & 31, og = t >> 5;      /* og 0..7 -> cc = og*8+k */
  float acc[8];
  #pragma unroll
  for (int k = 0; k < 8; k++) acc[k] = 0.f;
  for (int c = 0; c < 128; c++) {
    float xv = Xs[(c<<5) + n];
    const float* wrow = wt + (c<<6) + og*8;
    float4 wa = *(const float4*)wrow;
    float4 wb = *(const float4*)(wrow + 4);
    acc[0]+=wa.x*xv; acc[1]+=wa.y*xv; acc[2]+=wa.z*xv; acc[3]+=wa.w*xv;
    acc[4]+=wb.x*xv; acc[5]+=wb.y*xv; acc[6]+=wb.z*xv; acc[7]+=wb.w*xv;
  }
  #pragma unroll
  for (int k = 0; k < 8; k++)
    out[((size_t)(b*64 + og*8 + k))*NN + n0 + n] = acc[k];
}

/* ---- 2x2 maxpool f32 [b][64][96][96] -> [b][64][48][48] ---- */
__global__ __launch_bounds__(256) void k_pool(const float* __restrict__ in, float* __restrict__ out)
{
  int t = blockIdx.x*256 + threadIdx.x;   /* 589824 */
  int J = t % 48; int r = t/48; int I = r % 48; r /= 48; int cc = r & 63; int b = r >> 6;
  const float* p = in + ((size_t)(b*64+cc))*NN + (size_t)(2*I)*96 + 2*J;
  float m = fmaxf(fmaxf(p[0],p[1]), fmaxf(p[96],p[97]));
  out[((size_t)(b*64+cc))*MM + I*48 + J] = m;
}

/* ---- MFMA flash attention (bf16 inputs, f32 accum).
   Block: 64 queries (4 waves x 16), keys chunked by 64.
   LDS u16 map:  phi_T [k 64][72]  @0      (9216 B)
                 g_l   [cc 64][72] @4608   (9216 B)
                 P_l   per wave [16 q][72] @9216+wv*1152
   epilogue reuses LDS as f32 [wave][64 cc][20] for coalesced O store. ---- */
__global__ __launch_bounds__(256) void k_attn(const float* __restrict__ TH,
    const float* __restrict__ PH, const float* __restrict__ G, float* __restrict__ OUT)
{
  __shared__ __align__(16) u16 sm[13824];   /* 27648 B */
  int t = threadIdx.x;
  int lane = t & 63, wv = t >> 6;
  int quad = lane >> 4, l15 = lane & 15;
  int b  = blockIdx.x / 144;
  int q0 = (blockIdx.x % 144) * 64;
  int qw = q0 + wv*16;

  /* theta A-fragments, TEMP pre-scaled: A[q=l15][c=half*32+quad*8+j] */
  bf16x8 afrag[2];
  #pragma unroll
  for (int h = 0; h < 2; h++)
    #pragma unroll
    for (int j = 0; j < 8; j++) {
      float v = TEMPF * TH[((size_t)(b*64 + h*32 + quad*8 + j))*NN + qw + l15];
      afrag[h][j] = (short)f2bf(v);
    }

  f32x4 oacc[4];
  #pragma unroll
  for (int ct = 0; ct < 4; ct++)
    #pragma unroll
    for (int r = 0; r < 4; r++) oacc[ct][r] = 0.f;
  float m_r[4], l_r[4];
  #pragma unroll
  for (int r = 0; r < 4; r++) { m_r[r] = -3.0e38f; l_r[r] = 0.f; }

  int kth = t & 63;          /* staging: k lane */
  int cg  = t >> 6;

  for (int k0 = 0; k0 < MM; k0 += 64) {
    __syncthreads();                       /* prev PV done before overwrite */
    /* stage phi_T[k][c] (transpose f32->bf16) */
    #pragma unroll
    for (int h = 0; h < 2; h++) {
      int c0 = cg*16 + h*8;
      u32 pk[4];
      #pragma unroll
      for (int p = 0; p < 4; p++) {
        float f0 = PH[((size_t)(b*64 + c0 + 2*p    ))*MM + k0 + kth];
        float f1 = PH[((size_t)(b*64 + c0 + 2*p + 1))*MM + k0 + kth];
        pk[p] = pkbf(f0, f1);
      }
      *(uint4*)&sm[kth*72 + c0] = make_uint4(pk[0],pk[1],pk[2],pk[3]);
    }
    /* stage g_l[cc][k] (same layout as global) */
    {
      int cc = t >> 2, kq = (t & 3) << 4;
      const float* gp = &G[((size_t)(b*64 + cc))*MM + k0 + kq];
      u32 w[8];
      #pragma unroll
      for (int p = 0; p < 8; p++) w[p] = pkbf(gp[2*p], gp[2*p+1]);
      *(uint4*)&sm[4608 + cc*72 + kq]     = make_uint4(w[0],w[1],w[2],w[3]);
      *(uint4*)&sm[4608 + cc*72 + kq + 8] = make_uint4(w[4],w[5],w[6],w[7]);
    }
    __syncthreads();

    /* QK^T: 4 key-tiles x (2 MFMA over c) -> S[q=quad*4+r][key=kt*16+l15] */
    f32x4 s[4];
    #pragma unroll
    for (int kt = 0; kt < 4; kt++) {
      f32x4 acc;
      #pragma unroll
      for (int r = 0; r < 4; r++) acc[r] = 0.f;
      #pragma unroll
      for (int h = 0; h < 2; h++) {
        bf16x8 bfrag = *(const bf16x8*)&sm[(kt*16 + l15)*72 + h*32 + quad*8];
        acc = __builtin_amdgcn_mfma_f32_16x16x32_bf16(afrag[h], bfrag, acc, 0, 0, 0);
      }
      s[kt] = acc;
    }

    /* online softmax, per row r (q = quad*4+r), reduce over 16 lanes + 4 tiles */
    float al[4];
    #pragma unroll
    for (int r = 0; r < 4; r++) {
      float mx = fmaxf(fmaxf(s[0][r], s[1][r]), fmaxf(s[2][r], s[3][r]));
      #pragma unroll
      for (int d = 1; d < 16; d <<= 1) mx = fmaxf(mx, __shfl_xor(mx, d));
      float mn = fmaxf(m_r[r], mx);
      float a  = __expf(m_r[r] - mn);
      m_r[r] = mn;
      float ps = 0.f;
      #pragma unroll
      for (int kt = 0; kt < 4; kt++) {
        float p = __expf(s[kt][r] - mn);
        s[kt][r] = p; ps += p;
      }
      #pragma unroll
      for (int d = 1; d < 16; d <<= 1) ps += __shfl_xor(ps, d);
      l_r[r] = l_r[r]*a + ps;
      al[r] = a;
    }
    /* P -> per-wave LDS (bf16), rescale O */
    #pragma unroll
    for (int kt = 0; kt < 4; kt++)
      #pragma unroll
      for (int r = 0; r < 4; r++)
        sm[9216 + wv*1152 + (quad*4 + r)*72 + kt*16 + l15] = f2bf(s[kt][r]);
    #pragma unroll
    for (int ct = 0; ct < 4; ct++)
      #pragma unroll
      for (int r = 0; r < 4; r++) oacc[ct][r] *= al[r];

    /* PV: A = P[q=l15][key=h*32+quad*8+j], B = g[key][cc=ct*16+l15] */
    bf16x8 pf[2];
    #pragma unroll
    for (int h = 0; h < 2; h++)
      pf[h] = *(const bf16x8*)&sm[9216 + wv*1152 + l15*72 + h*32 + quad*8];
    #pragma unroll
    for (int ct = 0; ct < 4; ct++)
      #pragma unroll
      for (int h = 0; h < 2; h++) {
        bf16x8 gf = *(const bf16x8*)&sm[4608 + (ct*16 + l15)*72 + h*32 + quad*8];
        oacc[ct] = __builtin_amdgcn_mfma_f32_16x16x32_bf16(pf[h], gf, oacc[ct], 0, 0, 0);
      }
  }

  __syncthreads();   /* all waves done with phi/g/P regions */
  /* normalize + transpose through LDS for coalesced store */
  float inv[4];
  #pragma unroll
  for (int r = 0; r < 4; r++) inv[r] = 1.0f / l_r[r];
  float* ol = (float*)sm + wv*1280;      /* [cc 64][20] */
  #pragma unroll
  for (int ct = 0; ct < 4; ct++)
    #pragma unroll
    for (int r = 0; r < 4; r++)
      ol[(ct*16 + l15)*20 + quad*4 + r] = oacc[ct][r] * inv[r];
  __syncthreads();
  const float* orow = ol + lane*20;      /* cc = lane */
  float4 v0 = *(const float4*)(orow);
  float4 v1 = *(const float4*)(orow + 4);
  float4 v2 = *(const float4*)(orow + 8);
  float4 v3 = *(const float4*)(orow + 12);
  float* dst = &OUT[((size_t)(b*64 + lane))*NN + qw];
  *(float4*)(dst)      = v0;
  *(float4*)(dst + 4)  = v1;
  *(float4*)(dst + 8)  = v2;
  *(float4*)(dst + 12) = v3;
}

/* ---- o-projection 64->128, swizzled store into k_up block-own prefixes:
   ofin[b][o][i][j] -> dout[b slab][plane o>>2][2i+((o>>1)&1)][2j+(o&1)] ---- */
__global__ __launch_bounds__(256) void k_oconv(const float* __restrict__ X,
    const float* __restrict__ OW, float* __restrict__ dout)
{
  __shared__ __align__(16) float Xs[64*64];    /* [cc][64 n] 16KB */
  __shared__ __align__(16) float wt[64*128];   /* [cc][o]    32KB */
  int b  = blockIdx.x / 144;
  int n0 = (blockIdx.x % 144) * 64;
  int t  = threadIdx.x;
  for (int idx = t; idx < 8192; idx += 256) {
    int cc = idx >> 7, o = idx & 127;
    wt[idx] = OW[o*64 + cc];
  }
  for (int idx = t; idx < 1024; idx += 256) {  /* 64 rows x 16 float4 */
    int cc = idx >> 4, wq = idx & 15;
    ((float4*)Xs)[idx] = *(const float4*)&X[((size_t)(b*64 + cc))*NN + n0 + wq*4];
  }
  __syncthreads();
  int n = t & 63, og = t >> 6;       /* og 0..3 -> o = og*32+k */
  float acc[32];
  #pragma unroll
  for (int k = 0; k < 32; k++) acc[k] = 0.f;
  for (int cc = 0; cc < 64; cc++) {
    float xv = Xs[(cc << 6) + n];
    const float* wrow = wt + (cc << 7) + og*32;
    #pragma unroll
    for (int k = 0; k < 32; k++) acc[k] += wrow[k]*xv;
  }
  int ng = n0 + n;
  int i = ng / 96, j = ng - (ng/96)*96;
  #pragma unroll
  for (int k = 0; k < 32; k++) {
    int o = og*32 + k;
    size_t addr = (size_t)b*SLABF + (size_t)(o>>2)*HW
                + (size_t)(2*i + ((o>>1)&1))*192 + 2*j + (o&1);
    dout[addr] = acc[k];
  }
}

/* ---- up convtranspose + bias + gamma*y, f32, in-place over d_out. ---- */
__global__ __launch_bounds__(256) void k_up(float* __restrict__ dout,
    const float* __restrict__ upw, const float* __restrict__ upb,
    const float* __restrict__ Y, const float* __restrict__ gamma_p)
{
  __shared__ __align__(16) float o_s[128*96];   /* [c][j] 48KB */
  int blk = blockIdx.x;
  int b = blk / 96, i = blk - b*96;
  int t = threadIdx.x;
  size_t slab = (size_t)b*SLABF;
  const float* src = dout + slab + (size_t)(2*i)*192;

  /* phase 0: unswizzle own prefix -> LDS */
  for (int idx = t; idx < 12288; idx += 256) {   /* 32 planes x 2 rows x 192 */
    int run = idx / 384, rem = idx - run*384;
    int r = rem / 192, col = rem - r*192;
    float v = src[(size_t)run*HW + r*192 + col];
    int o = 4*run + 2*r + (col&1);
    o_s[o*96 + (col>>1)] = v;
  }
  __syncthreads();

  int op5 = t >> 3, jg = t & 7;
  float gm = *gamma_p;

  for (int opc = 0; opc < 4; opc++) {
    int op = opc*32 + op5;
    float bias = upb[op];
    size_t obase = slab + (size_t)op*HW + (size_t)(2*i)*192;
    for (int s = 0; s < 3; s++) {
      int j0 = jg*12 + s*4;
      float a00[4], a01[4], a10[4], a11[4];
      #pragma unroll
      for (int jj = 0; jj < 4; jj++) { a00[jj]=0.f; a01[jj]=0.f; a10[jj]=0.f; a11[jj]=0.f; }
      for (int c = 0; c < 128; c++) {
        float4 ov = *(const float4*)&o_s[c*96 + j0];
        float4 wv = *(const float4*)&upw[((size_t)c*128 + op)*4];  /* w00 w01 w10 w11 */
        a00[0]+=ov.x*wv.x; a01[0]+=ov.x*wv.y; a10[0]+=ov.x*wv.z; a11[0]+=ov.x*wv.w;
        a00[1]+=ov.y*wv.x; a01[1]+=ov.y*wv.y; a10[1]+=ov.y*wv.z; a11[1]+=ov.y*wv.w;
        a00[2]+=ov.z*wv.x; a01[2]+=ov.z*wv.y; a10[2]+=ov.z*wv.z; a11[2]+=ov.z*wv.w;
        a00[3]+=ov.w*wv.x; a01[3]+=ov.w*wv.y; a10[3]+=ov.w*wv.z; a11[3]+=ov.w*wv.w;
      }
      size_t p0 = obase + 2*j0;          /* row 2i,  col 2*j0 */
      size_t p1 = p0 + 192;              /* row 2i+1 */
      float4 y0a = *(const float4*)&Y[p0];
      float4 y0b = *(const float4*)&Y[p0 + 4];
      float4 y1a = *(const float4*)&Y[p1];
      float4 y1b = *(const float4*)&Y[p1 + 4];
      *(float4*)&dout[p0]     = make_float4(a00[0]+bias+gm*y0a.x, a01[0]+bias+gm*y0a.y,
                                            a00[1]+bias+gm*y0a.z, a01[1]+bias+gm*y0a.w);
      *(float4*)&dout[p0 + 4] = make_float4(a00[2]+bias+gm*y0b.x, a01[2]+bias+gm*y0b.y,
                                            a00[3]+bias+gm*y0b.z, a01[3]+bias+gm*y0b.w);
      *(float4*)&dout[p1]     = make_float4(a10[0]+bias+gm*y1a.x, a11[0]+bias+gm*y1a.y,
                                            a10[1]+bias+gm*y1a.z, a11[1]+bias+gm*y1a.w);
      *(float4*)&dout[p1 + 4] = make_float4(a10[2]+bias+gm*y1b.x, a11[2]+bias+gm*y1b.y,
                                            a10[3]+bias+gm*y1b.z, a11[3]+bias+gm*y1b.w);
    }
  }
}

extern "C" void kernel_launch(void* const* d_in, const int* in_sizes, int n_in,
                              void* d_out, int out_size, void* d_ws, size_t ws_size,
                              hipStream_t stream) {
  const float* x_in  = (const float*)d_in[0];
  const float* y_in  = (const float*)d_in[1];
  const float* d0w   = (const float*)d_in[2];
  const float* d0b   = (const float*)d_in[3];
  const float* d1w   = (const float*)d_in[4];
  const float* d1b   = (const float*)d_in[5];
  const float* thw   = (const float*)d_in[6];
  const float* phw   = (const float*)d_in[7];
  const float* gw    = (const float*)d_in[8];
  const float* ow    = (const float*)d_in[9];
  const float* upw   = (const float*)d_in[10];
  const float* upb   = (const float*)d_in[11];
  const float* gamma = (const float*)d_in[12];
  float* out = (float*)d_out;

  /* d_ws UNUSED; d_in READ-ONLY; all scratch in d_out (see offset map). */
  k_down <<<768,  256, 0, stream>>>(x_in, d0w, d0b, out + OFF_X);
  k_down <<<768,  256, 0, stream>>>(y_in, d1w, d1b, out + OFF_Y);
  k_conv <<<1152, 256, 0, stream>>>(out + OFF_X, thw, out + OFF_TH);
  k_conv <<<1152, 256, 0, stream>>>(out + OFF_X, phw, out + OFF_TP);
  k_pool <<<2304, 256, 0, stream>>>(out + OFF_TP, out + OFF_PH);
  k_conv <<<1152, 256, 0, stream>>>(out + OFF_Y, gw, out + OFF_TP);
  k_pool <<<2304, 256, 0, stream>>>(out + OFF_TP, out + OFF_G);
  k_attn <<<576,  256, 0, stream>>>(out + OFF_TH, out + OFF_PH, out + OFF_G, out + OFF_OM);
  k_oconv<<<576,  256, 0, stream>>>(out + OFF_OM, ow, out);
  k_up   <<<384,  256, 0, stream>>>(out, upw, upb, y_in, gamma);
}

// Round 2
// 720.120 us; speedup vs baseline: 1.7370x; 1.0927x over previous
//
#include <hip/hip_runtime.h>
#include <hip/hip_bf16.h>

#define NN    9216      /* 96*96   */
#define MM    2304      /* 48*48   */
#define HW    36864     /* 192*192 */
#define SLABF 4718592   /* f32 per batch slab of output: 128*192*192 */
#define TEMPF 5.0f

/* d_out f32 offsets (scratch; lifetimes verified):
   x    [0        , 4718592)   dead after theta/phi convs
   y    [4718592  , 9437184)   dead after g conv
   th   [9437184  , 11796480)  dead after attn
   tp   [11796480 , 14155776)  pre-pool temp, dead after pools
   ph   [14155776 , 14745600)  dead after attn
   g    [14745600 , 15335424)  dead after attn
   omap [15335424 , 17694720)  attn out, read by oconv
   ofin : swizzled into plane-0..31 prefix of each batch slab (race-free k_up) */
#define OFF_X   0
#define OFF_Y   4718592
#define OFF_TH  9437184
#define OFF_TP  11796480
#define OFF_PH  14155776
#define OFF_G   14745600
#define OFF_OM  15335424

typedef unsigned short u16;
typedef unsigned int   u32;
typedef __attribute__((ext_vector_type(8))) short bf16x8;
typedef __attribute__((ext_vector_type(4))) float f32x4;

__device__ __forceinline__ u16 f2bf(float f){
  u32 u; __builtin_memcpy(&u,&f,4);
  u32 lsb = (u>>16)&1u; u += 0x7fffu + lsb;   /* RNE */
  return (u16)(u>>16);
}
__device__ __forceinline__ u32 pkbf(float a, float b){
  union { __hip_bfloat162 h; u32 u; } v;
  v.h = __float22bfloat162_rn(make_float2(a,b));
  return v.u;
}

/* ---- down conv k=2 s=2, 128->128, f32, LDS-tiled ----
   Block = (b, i, jt): 128 o x 48 output cols of row i.
   Stage 32 channels/chunk into LDS, double-buffered (24.6 KB x2 -> 3 blk/CU).
   LDS layout row-interleaved so each thread's 2x6 patch = 3x ds_read_b128.
   Thread tile 8 o x 3 j -> 96 FMA : 3 ds_b128 per channel (VALU-bound).
   T14 async-stage split: chunk+1 global loads issued before compute barrier. */
__global__ __launch_bounds__(256) void k_down(const float* __restrict__ in,
    const float* __restrict__ w, const float* __restrict__ bias, float* __restrict__ out)
{
  __shared__ __align__(16) float xs[2][6144];   /* [32 c][96 col][2 r] interleaved */
  int blk = blockIdx.x;
  int jt = blk & 1;                  /* 2 col-tiles of 48 */
  int r1 = blk >> 1;
  int i  = r1 % 96; int b = r1 / 96;
  int t  = threadIdx.x;

  const float* src = in + (size_t)b*128*HW + (size_t)(2*i)*192 + jt*96;

  /* stage task split: 768 tasks/chunk = 3 per thread; idx -> (cl, q) */
  int cl[3], qq[3];
  #pragma unroll
  for (int k = 0; k < 3; k++) {
    int idx = t + k*256;
    cl[k] = idx / 24;                /* channel-in-chunk 0..31 */
    qq[k] = idx - cl[k]*24;          /* col-group of 4, 0..23  */
  }

  float4 va[3], vb[3];
  /* prologue: stage chunk 0 */
  #pragma unroll
  for (int k = 0; k < 3; k++) {
    const float* p = src + (size_t)cl[k]*HW + qq[k]*4;
    va[k] = *(const float4*)p;
    vb[k] = *(const float4*)(p + 192);
  }
  #pragma unroll
  for (int k = 0; k < 3; k++) {
    float* d = &xs[0][cl[k]*192 + qq[k]*8];
    *(float4*)d       = make_float4(va[k].x, vb[k].x, va[k].y, vb[k].y);
    *(float4*)(d + 4) = make_float4(va[k].z, vb[k].z, va[k].w, vb[k].w);
  }

  int og = t >> 4, jg = t & 15;      /* 16 og x 8 o ; 16 jg x 3 j */
  int o0 = og * 8;
  float acc[8][3];
  #pragma unroll
  for (int oo = 0; oo < 8; oo++)
    #pragma unroll
    for (int jj = 0; jj < 3; jj++) acc[oo][jj] = 0.f;

  const float* wbase = w + (size_t)o0*512;   /* w[o][c][4] */

  for (int ch = 0; ch < 4; ch++) {
    /* issue next chunk's global loads early (hide under compute) */
    if (ch < 3) {
      #pragma unroll
      for (int k = 0; k < 3; k++) {
        const float* p = src + (size_t)((ch+1)*32 + cl[k])*HW + qq[k]*4;
        va[k] = *(const float4*)p;
        vb[k] = *(const float4*)(p + 192);
      }
    }
    __syncthreads();                 /* chunk ch LDS writes visible */

    const float* xb = xs[ch & 1];
    const float* wc = wbase + (ch*32)*4;
    for (int c = 0; c < 32; c++) {
      const float* xp = xb + c*192 + jg*12;
      float4 xv0 = *(const float4*)(xp);
      float4 xv1 = *(const float4*)(xp + 4);
      float4 xv2 = *(const float4*)(xp + 8);
      const float* wp = wc + c*4;
      #pragma unroll
      for (int oo = 0; oo < 8; oo++) {
        float4 wv = *(const float4*)(wp + oo*512);
        acc[oo][0] += xv0.x*wv.x + xv0.z*wv.y + xv0.y*wv.z + xv0.w*wv.w;
        acc[oo][1] += xv1.x*wv.x + xv1.z*wv.y + xv1.y*wv.z + xv1.w*wv.w;
        acc[oo][2] += xv2.x*wv.x + xv2.z*wv.y + xv2.y*wv.z + xv2.w*wv.w;
      }
    }

    /* write next chunk into the other buffer, after compute (T14 split) */
    if (ch < 3) {
      #pragma unroll
      for (int k = 0; k < 3; k++) {
        float* d = &xs[(ch+1) & 1][cl[k]*192 + qq[k]*8];
        *(float4*)d       = make_float4(va[k].x, vb[k].x, va[k].y, vb[k].y);
        *(float4*)(d + 4) = make_float4(va[k].z, vb[k].z, va[k].w, vb[k].w);
      }
    }
  }

  /* epilogue: out[b][o][i][jt*48 + jg*3 + {0,1,2}] */
  #pragma unroll
  for (int oo = 0; oo < 8; oo++) {
    int o = o0 + oo;
    float bv = bias[o];
    float* op = out + ((size_t)(b*128 + o))*NN + i*96 + jt*48 + jg*3;
    op[0] = acc[oo][0] + bv;
    op[1] = acc[oo][1] + bv;
    op[2] = acc[oo][2] + bv;
  }
}

/* ---- 1x1 conv 128->64: out[b][cc][n] = sum_c W[cc][c]*X[b][c][n] ---- */
__global__ __launch_bounds__(256) void k_conv(const float* __restrict__ X,
    const float* __restrict__ WG, float* __restrict__ out)
{
  __shared__ __align__(16) float Xs[128*32];   /* [c][32 n] 16KB */
  __shared__ __align__(16) float wt[128*64];   /* [c][cc]   32KB */
  int b  = blockIdx.x / 288;
  int n0 = (blockIdx.x % 288) * 32;
  int t  = threadIdx.x;
  for (int idx = t; idx < 8192; idx += 256) {
    int c = idx >> 6, cc = idx & 63;
    wt[idx] = WG[cc*128 + c];
  }
  for (int idx = t; idx < 1024; idx += 256) {  /* 128 rows x 8 float4 */
    int c = idx >> 3, wq = idx & 7;
    ((float4*)Xs)[idx] = *(const float4*)&X[((size_t)(b*128 + c))*NN + n0 + wq*4];
  }
  __syncthreads();
  int n = t & 31, og = t >> 5;      /* og 0..7 -> cc = og*8+k */
  float acc[8];
  #pragma unroll
  for (int k = 0; k < 8; k++) acc[k] = 0.f;
  for (int c = 0; c < 128; c++) {
    float xv = Xs[(c<<5) + n];
    const float* wrow = wt + (c<<6) + og*8;
    float4 wa = *(const float4*)wrow;
    float4 wb = *(const float4*)(wrow + 4);
    acc[0]+=wa.x*xv; acc[1]+=wa.y*xv; acc[2]+=wa.z*xv; acc[3]+=wa.w*xv;
    acc[4]+=wb.x*xv; acc[5]+=wb.y*xv; acc[6]+=wb.z*xv; acc[7]+=wb.w*xv;
  }
  #pragma unroll
  for (int k = 0; k < 8; k++)
    out[((size_t)(b*64 + og*8 + k))*NN + n0 + n] = acc[k];
}

/* ---- 2x2 maxpool f32 [b][64][96][96] -> [b][64][48][48] ---- */
__global__ __launch_bounds__(256) void k_pool(const float* __restrict__ in, float* __restrict__ out)
{
  int t = blockIdx.x*256 + threadIdx.x;   /* 589824 */
  int J = t % 48; int r = t/48; int I = r % 48; r /= 48; int cc = r & 63; int b = r >> 6;
  const float* p = in + ((size_t)(b*64+cc))*NN + (size_t)(2*I)*96 + 2*J;
  float m = fmaxf(fmaxf(p[0],p[1]), fmaxf(p[96],p[97]));
  out[((size_t)(b*64+cc))*MM + I*48 + J] = m;
}

/* ---- MFMA flash attention (bf16 inputs, f32 accum).
   Block: 64 queries (4 waves x 16), keys chunked by 64.
   LDS u16 map:  phi_T [k 64][72]  @0      (9216 B)
                 g_l   [cc 64][72] @4608   (9216 B)
                 P_l   per wave [16 q][72] @9216+wv*1152
   epilogue reuses LDS as f32 [wave][64 cc][20] for coalesced O store. ---- */
__global__ __launch_bounds__(256) void k_attn(const float* __restrict__ TH,
    const float* __restrict__ PH, const float* __restrict__ G, float* __restrict__ OUT)
{
  __shared__ __align__(16) u16 sm[13824];   /* 27648 B */
  int t = threadIdx.x;
  int lane = t & 63, wv = t >> 6;
  int quad = lane >> 4, l15 = lane & 15;
  int b  = blockIdx.x / 144;
  int q0 = (blockIdx.x % 144) * 64;
  int qw = q0 + wv*16;

  /* theta A-fragments, TEMP pre-scaled: A[q=l15][c=half*32+quad*8+j] */
  bf16x8 afrag[2];
  #pragma unroll
  for (int h = 0; h < 2; h++)
    #pragma unroll
    for (int j = 0; j < 8; j++) {
      float v = TEMPF * TH[((size_t)(b*64 + h*32 + quad*8 + j))*NN + qw + l15];
      afrag[h][j] = (short)f2bf(v);
    }

  f32x4 oacc[4];
  #pragma unroll
  for (int ct = 0; ct < 4; ct++)
    #pragma unroll
    for (int r = 0; r < 4; r++) oacc[ct][r] = 0.f;
  float m_r[4], l_r[4];
  #pragma unroll
  for (int r = 0; r < 4; r++) { m_r[r] = -3.0e38f; l_r[r] = 0.f; }

  int kth = t & 63;          /* staging: k lane */
  int cg  = t >> 6;

  for (int k0 = 0; k0 < MM; k0 += 64) {
    __syncthreads();                       /* prev PV done before overwrite */
    /* stage phi_T[k][c] (transpose f32->bf16) */
    #pragma unroll
    for (int h = 0; h < 2; h++) {
      int c0 = cg*16 + h*8;
      u32 pk[4];
      #pragma unroll
      for (int p = 0; p < 4; p++) {
        float f0 = PH[((size_t)(b*64 + c0 + 2*p    ))*MM + k0 + kth];
        float f1 = PH[((size_t)(b*64 + c0 + 2*p + 1))*MM + k0 + kth];
        pk[p] = pkbf(f0, f1);
      }
      *(uint4*)&sm[kth*72 + c0] = make_uint4(pk[0],pk[1],pk[2],pk[3]);
    }
    /* stage g_l[cc][k] (same layout as global) */
    {
      int cc = t >> 2, kq = (t & 3) << 4;
      const float* gp = &G[((size_t)(b*64 + cc))*MM + k0 + kq];
      u32 w[8];
      #pragma unroll
      for (int p = 0; p < 8; p++) w[p] = pkbf(gp[2*p], gp[2*p+1]);
      *(uint4*)&sm[4608 + cc*72 + kq]     = make_uint4(w[0],w[1],w[2],w[3]);
      *(uint4*)&sm[4608 + cc*72 + kq + 8] = make_uint4(w[4],w[5],w[6],w[7]);
    }
    __syncthreads();

    /* QK^T: 4 key-tiles x (2 MFMA over c) -> S[q=quad*4+r][key=kt*16+l15] */
    f32x4 s[4];
    #pragma unroll
    for (int kt = 0; kt < 4; kt++) {
      f32x4 acc;
      #pragma unroll
      for (int r = 0; r < 4; r++) acc[r] = 0.f;
      #pragma unroll
      for (int h = 0; h < 2; h++) {
        bf16x8 bfrag = *(const bf16x8*)&sm[(kt*16 + l15)*72 + h*32 + quad*8];
        acc = __builtin_amdgcn_mfma_f32_16x16x32_bf16(afrag[h], bfrag, acc, 0, 0, 0);
      }
      s[kt] = acc;
    }

    /* online softmax, per row r (q = quad*4+r), reduce over 16 lanes + 4 tiles */
    float al[4];
    #pragma unroll
    for (int r = 0; r < 4; r++) {
      float mx = fmaxf(fmaxf(s[0][r], s[1][r]), fmaxf(s[2][r], s[3][r]));
      #pragma unroll
      for (int d = 1; d < 16; d <<= 1) mx = fmaxf(mx, __shfl_xor(mx, d));
      float mn = fmaxf(m_r[r], mx);
      float a  = __expf(m_r[r] - mn);
      m_r[r] = mn;
      float ps = 0.f;
      #pragma unroll
      for (int kt = 0; kt < 4; kt++) {
        float p = __expf(s[kt][r] - mn);
        s[kt][r] = p; ps += p;
      }
      #pragma unroll
      for (int d = 1; d < 16; d <<= 1) ps += __shfl_xor(ps, d);
      l_r[r] = l_r[r]*a + ps;
      al[r] = a;
    }
    /* P -> per-wave LDS (bf16), rescale O */
    #pragma unroll
    for (int kt = 0; kt < 4; kt++)
      #pragma unroll
      for (int r = 0; r < 4; r++)
        sm[9216 + wv*1152 + (quad*4 + r)*72 + kt*16 + l15] = f2bf(s[kt][r]);
    #pragma unroll
    for (int ct = 0; ct < 4; ct++)
      #pragma unroll
      for (int r = 0; r < 4; r++) oacc[ct][r] *= al[r];

    /* PV: A = P[q=l15][key=h*32+quad*8+j], B = g[key][cc=ct*16+l15] */
    bf16x8 pf[2];
    #pragma unroll
    for (int h = 0; h < 2; h++)
      pf[h] = *(const bf16x8*)&sm[9216 + wv*1152 + l15*72 + h*32 + quad*8];
    #pragma unroll
    for (int ct = 0; ct < 4; ct++)
      #pragma unroll
      for (int h = 0; h < 2; h++) {
        bf16x8 gf = *(const bf16x8*)&sm[4608 + (ct*16 + l15)*72 + h*32 + quad*8];
        oacc[ct] = __builtin_amdgcn_mfma_f32_16x16x32_bf16(pf[h], gf, oacc[ct], 0, 0, 0);
      }
  }

  __syncthreads();   /* all waves done with phi/g/P regions */
  /* normalize + transpose through LDS for coalesced store */
  float inv[4];
  #pragma unroll
  for (int r = 0; r < 4; r++) inv[r] = 1.0f / l_r[r];
  float* ol = (float*)sm + wv*1280;      /* [cc 64][20] */
  #pragma unroll
  for (int ct = 0; ct < 4; ct++)
    #pragma unroll
    for (int r = 0; r < 4; r++)
      ol[(ct*16 + l15)*20 + quad*4 + r] = oacc[ct][r] * inv[r];
  __syncthreads();
  const float* orow = ol + lane*20;      /* cc = lane */
  float4 v0 = *(const float4*)(orow);
  float4 v1 = *(const float4*)(orow + 4);
  float4 v2 = *(const float4*)(orow + 8);
  float4 v3 = *(const float4*)(orow + 12);
  float* dst = &OUT[((size_t)(b*64 + lane))*NN + qw];
  *(float4*)(dst)      = v0;
  *(float4*)(dst + 4)  = v1;
  *(float4*)(dst + 8)  = v2;
  *(float4*)(dst + 12) = v3;
}

/* ---- o-projection 64->128, swizzled store into k_up block-own prefixes:
   ofin[b][o][i][j] -> dout[b slab][plane o>>2][2i+((o>>1)&1)][2j+(o&1)] ---- */
__global__ __launch_bounds__(256) void k_oconv(const float* __restrict__ X,
    const float* __restrict__ OW, float* __restrict__ dout)
{
  __shared__ __align__(16) float Xs[64*64];    /* [cc][64 n] 16KB */
  __shared__ __align__(16) float wt[64*128];   /* [cc][o]    32KB */
  int b  = blockIdx.x / 144;
  int n0 = (blockIdx.x % 144) * 64;
  int t  = threadIdx.x;
  for (int idx = t; idx < 8192; idx += 256) {
    int cc = idx >> 7, o = idx & 127;
    wt[idx] = OW[o*64 + cc];
  }
  for (int idx = t; idx < 1024; idx += 256) {  /* 64 rows x 16 float4 */
    int cc = idx >> 4, wq = idx & 15;
    ((float4*)Xs)[idx] = *(const float4*)&X[((size_t)(b*64 + cc))*NN + n0 + wq*4];
  }
  __syncthreads();
  int n = t & 63, og = t >> 6;       /* og 0..3 -> o = og*32+k */
  float acc[32];
  #pragma unroll
  for (int k = 0; k < 32; k++) acc[k] = 0.f;
  for (int cc = 0; cc < 64; cc++) {
    float xv = Xs[(cc << 6) + n];
    const float* wrow = wt + (cc << 7) + og*32;
    #pragma unroll
    for (int k = 0; k < 32; k++) acc[k] += wrow[k]*xv;
  }
  int ng = n0 + n;
  int i = ng / 96, j = ng - (ng/96)*96;
  #pragma unroll
  for (int k = 0; k < 32; k++) {
    int o = og*32 + k;
    size_t addr = (size_t)b*SLABF + (size_t)(o>>2)*HW
                + (size_t)(2*i + ((o>>1)&1))*192 + 2*j + (o&1);
    dout[addr] = acc[k];
  }
}

/* ---- up convtranspose + bias + gamma*y, f32, in-place over d_out. ----
   R1 rewrite: block = (b, i, jh) where jh picks output cols [jh*96, jh*96+96).
   k=2 s=2 transpose conv: those outputs depend ONLY on o cols [jh*48,+48),
   stored swizzled in exactly the region this block overwrites -> race-free.
   LDS halves to 24KB -> 6 blocks/CU (24 waves/CU vs old 4-8).
   Threads: op_l = t&31 (lanes contiguous in op -> per-c weight read is one
   coalesced 512B load), jg = t>>5 (o_s read = 32-lane broadcast, free).
   4 op-chunks x (1 op x 6 in-cols = 24 acc), 24 FMA : 3 ds_b64 : 1 global/c. */
__global__ __launch_bounds__(256) void k_up(float* __restrict__ dout,
    const float* __restrict__ upw, const float* __restrict__ upb,
    const float* __restrict__ Y, const float* __restrict__ gamma_p)
{
  __shared__ __align__(16) float o_s[128*48];   /* [c][48 j] 24KB */
  int blk = blockIdx.x;
  int jh = blk & 1;
  int r1 = blk >> 1;
  int i = r1 % 96, b = r1 / 96;
  int t = threadIdx.x;
  size_t slab = (size_t)b*SLABF;
  const float* src = dout + slab + (size_t)(2*i)*192 + jh*96;

  /* phase 0: unswizzle own half-prefix -> LDS (32 planes x 2 rows x 96 cols) */
  for (int idx = t; idx < 6144; idx += 256) {
    int run = idx / 192, rem = idx - run*192;
    int r = rem / 96, cl = rem - r*96;
    float v = src[(size_t)run*HW + r*192 + cl];
    int o = 4*run + 2*r + (cl&1);
    o_s[o*48 + (cl>>1)] = v;
  }
  __syncthreads();

  int op_l = t & 31, jg = t >> 5;   /* 32 op-lanes x 8 col-groups of 6 */
  float gm = *gamma_p;

  for (int oc = 0; oc < 4; oc++) {
    int op = oc*32 + op_l;
    float a0[12], a1[12];            /* row 2i / 2i+1, 12 out cols */
    #pragma unroll
    for (int k = 0; k < 12; k++) { a0[k] = 0.f; a1[k] = 0.f; }

    const float* wp = upw + (size_t)op*4;     /* stride 512 f32 per c */
    const float* xb = o_s + jg*6;
    for (int c = 0; c < 128; c++) {
      float4 wv = *(const float4*)(wp + (size_t)c*512);   /* w00 w01 w10 w11 */
      const float* xp = xb + c*48;
      float2 x01 = *(const float2*)(xp);
      float2 x23 = *(const float2*)(xp + 2);
      float2 x45 = *(const float2*)(xp + 4);
      a0[0] += x01.x*wv.x; a0[1] += x01.x*wv.y; a1[0] += x01.x*wv.z; a1[1] += x01.x*wv.w;
      a0[2] += x01.y*wv.x; a0[3] += x01.y*wv.y; a1[2] += x01.y*wv.z; a1[3] += x01.y*wv.w;
      a0[4] += x23.x*wv.x; a0[5] += x23.x*wv.y; a1[4] += x23.x*wv.z; a1[5] += x23.x*wv.w;
      a0[6] += x23.y*wv.x; a0[7] += x23.y*wv.y; a1[6] += x23.y*wv.z; a1[7] += x23.y*wv.w;
      a0[8] += x45.x*wv.x; a0[9] += x45.x*wv.y; a1[8] += x45.x*wv.z; a1[9] += x45.x*wv.w;
      a0[10]+= x45.y*wv.x; a0[11]+= x45.y*wv.y; a1[10]+= x45.y*wv.z; a1[11]+= x45.y*wv.w;
    }

    float bias = upb[op];
    size_t obase = slab + (size_t)op*HW + (size_t)(2*i)*192 + jh*96 + jg*12;
    float* p0 = dout + obase;
    float* p1 = p0 + 192;
    const float* y0 = Y + obase;
    const float* y1 = y0 + 192;
    #pragma unroll
    for (int q = 0; q < 3; q++) {
      float4 ya = *(const float4*)(y0 + 4*q);
      float4 yb = *(const float4*)(y1 + 4*q);
      *(float4*)(p0 + 4*q) = make_float4(a0[4*q+0]+bias+gm*ya.x, a0[4*q+1]+bias+gm*ya.y,
                                         a0[4*q+2]+bias+gm*ya.z, a0[4*q+3]+bias+gm*ya.w);
      *(float4*)(p1 + 4*q) = make_float4(a1[4*q+0]+bias+gm*yb.x, a1[4*q+1]+bias+gm*yb.y,
                                         a1[4*q+2]+bias+gm*yb.z, a1[4*q+3]+bias+gm*yb.w);
    }
  }
}

extern "C" void kernel_launch(void* const* d_in, const int* in_sizes, int n_in,
                              void* d_out, int out_size, void* d_ws, size_t ws_size,
                              hipStream_t stream) {
  const float* x_in  = (const float*)d_in[0];
  const float* y_in  = (const float*)d_in[1];
  const float* d0w   = (const float*)d_in[2];
  const float* d0b   = (const float*)d_in[3];
  const float* d1w   = (const float*)d_in[4];
  const float* d1b   = (const float*)d_in[5];
  const float* thw   = (const float*)d_in[6];
  const float* phw   = (const float*)d_in[7];
  const float* gw    = (const float*)d_in[8];
  const float* ow    = (const float*)d_in[9];
  const float* upw   = (const float*)d_in[10];
  const float* upb   = (const float*)d_in[11];
  const float* gamma = (const float*)d_in[12];
  float* out = (float*)d_out;

  /* d_ws UNUSED; d_in READ-ONLY; all scratch in d_out (see offset map). */
  k_down <<<768,  256, 0, stream>>>(x_in, d0w, d0b, out + OFF_X);
  k_down <<<768,  256, 0, stream>>>(y_in, d1w, d1b, out + OFF_Y);
  k_conv <<<1152, 256, 0, stream>>>(out + OFF_X, thw, out + OFF_TH);
  k_conv <<<1152, 256, 0, stream>>>(out + OFF_X, phw, out + OFF_TP);
  k_pool <<<2304, 256, 0, stream>>>(out + OFF_TP, out + OFF_PH);
  k_conv <<<1152, 256, 0, stream>>>(out + OFF_Y, gw, out + OFF_TP);
  k_pool <<<2304, 256, 0, stream>>>(out + OFF_TP, out + OFF_G);
  k_attn <<<576,  256, 0, stream>>>(out + OFF_TH, out + OFF_PH, out + OFF_G, out + OFF_OM);
  k_oconv<<<576,  256, 0, stream>>>(out + OFF_OM, ow, out);
  k_up   <<<768,  256, 0, stream>>>(out, upw, upb, y_in, gamma);
}

// Round 3
// 687.484 us; speedup vs baseline: 1.8195x; 1.0475x over previous
//
#include <hip/hip_runtime.h>
#include <hip/hip_bf16.h>

#define NN    9216      /* 96*96   */
#define MM    2304      /* 48*48   */
#define HW    36864     /* 192*192 */
#define SLABF 4718592   /* f32 per batch slab of output: 128*192*192 */
#define TEMPF 5.0f

/* d_out f32 offsets (scratch; lifetimes verified):
   x    [0        , 4718592)   dead after theta/phi convs; then attn PO partials
   y    [4718592  , 9437184)   dead after g conv; then attn m/l partials
   th   [9437184  , 11796480)  dead after attn
   tp   [11796480 , 14155776)  pre-pool temp, dead after pools
   ph   [14155776 , 14745600)  phiT bf16 [b][2304][64] (uses half region)
   g    [14745600 , 15335424)  g bf16 [b][64][2304]   (uses half region)
   omap [15335424 , 17694720)  merged attn out, read by oconv
   ofin : swizzled into plane-0..31 prefix of each batch slab (race-free k_up)
   Order: attn(writes PO@X, ML@Y) -> amerge(reads PO/ML, writes OM) ->
          oconv(reads OM, writes slab prefixes over X/Y/TH/PH/G) -> up. */
#define OFF_X   0
#define OFF_Y   4718592
#define OFF_TH  9437184
#define OFF_TP  11796480
#define OFF_PH  14155776
#define OFF_G   14745600
#define OFF_OM  15335424
#define POSZ    2359296   /* 4*64*9216: one split's partial O */
#define MLSZ    73728     /* 2*4*9216: m (or l) for both splits */

typedef unsigned short u16;
typedef unsigned int   u32;
typedef __attribute__((ext_vector_type(8))) short bf16x8;
typedef __attribute__((ext_vector_type(4))) float f32x4;

__device__ __forceinline__ u16 f2bf(float f){
  u32 u; __builtin_memcpy(&u,&f,4);
  u32 lsb = (u>>16)&1u; u += 0x7fffu + lsb;   /* RNE */
  return (u16)(u>>16);
}
__device__ __forceinline__ u32 pkbf(float a, float b){
  union { __hip_bfloat162 h; u32 u; } v;
  v.h = __float22bfloat162_rn(make_float2(a,b));
  return v.u;
}

/* ---- down conv k=2 s=2, 128->128, f32, LDS-tiled (R0 winner, unchanged) ---- */
__global__ __launch_bounds__(256) void k_down(const float* __restrict__ in,
    const float* __restrict__ w, const float* __restrict__ bias, float* __restrict__ out)
{
  __shared__ __align__(16) float xs[2][6144];   /* [32 c][96 col][2 r] interleaved */
  int blk = blockIdx.x;
  int jt = blk & 1;
  int r1 = blk >> 1;
  int i  = r1 % 96; int b = r1 / 96;
  int t  = threadIdx.x;

  const float* src = in + (size_t)b*128*HW + (size_t)(2*i)*192 + jt*96;

  int cl[3], qq[3];
  #pragma unroll
  for (int k = 0; k < 3; k++) {
    int idx = t + k*256;
    cl[k] = idx / 24;
    qq[k] = idx - cl[k]*24;
  }

  float4 va[3], vb[3];
  #pragma unroll
  for (int k = 0; k < 3; k++) {
    const float* p = src + (size_t)cl[k]*HW + qq[k]*4;
    va[k] = *(const float4*)p;
    vb[k] = *(const float4*)(p + 192);
  }
  #pragma unroll
  for (int k = 0; k < 3; k++) {
    float* d = &xs[0][cl[k]*192 + qq[k]*8];
    *(float4*)d       = make_float4(va[k].x, vb[k].x, va[k].y, vb[k].y);
    *(float4*)(d + 4) = make_float4(va[k].z, vb[k].z, va[k].w, vb[k].w);
  }

  int og = t >> 4, jg = t & 15;
  int o0 = og * 8;
  float acc[8][3];
  #pragma unroll
  for (int oo = 0; oo < 8; oo++)
    #pragma unroll
    for (int jj = 0; jj < 3; jj++) acc[oo][jj] = 0.f;

  const float* wbase = w + (size_t)o0*512;

  for (int ch = 0; ch < 4; ch++) {
    if (ch < 3) {
      #pragma unroll
      for (int k = 0; k < 3; k++) {
        const float* p = src + (size_t)((ch+1)*32 + cl[k])*HW + qq[k]*4;
        va[k] = *(const float4*)p;
        vb[k] = *(const float4*)(p + 192);
      }
    }
    __syncthreads();

    const float* xb = xs[ch & 1];
    const float* wc = wbase + (ch*32)*4;
    for (int c = 0; c < 32; c++) {
      const float* xp = xb + c*192 + jg*12;
      float4 xv0 = *(const float4*)(xp);
      float4 xv1 = *(const float4*)(xp + 4);
      float4 xv2 = *(const float4*)(xp + 8);
      const float* wp = wc + c*4;
      #pragma unroll
      for (int oo = 0; oo < 8; oo++) {
        float4 wv = *(const float4*)(wp + oo*512);
        acc[oo][0] += xv0.x*wv.x + xv0.z*wv.y + xv0.y*wv.z + xv0.w*wv.w;
        acc[oo][1] += xv1.x*wv.x + xv1.z*wv.y + xv1.y*wv.z + xv1.w*wv.w;
        acc[oo][2] += xv2.x*wv.x + xv2.z*wv.y + xv2.y*wv.z + xv2.w*wv.w;
      }
    }

    if (ch < 3) {
      #pragma unroll
      for (int k = 0; k < 3; k++) {
        float* d = &xs[(ch+1) & 1][cl[k]*192 + qq[k]*8];
        *(float4*)d       = make_float4(va[k].x, vb[k].x, va[k].y, vb[k].y);
        *(float4*)(d + 4) = make_float4(va[k].z, vb[k].z, va[k].w, vb[k].w);
      }
    }
  }

  #pragma unroll
  for (int oo = 0; oo < 8; oo++) {
    int o = o0 + oo;
    float bv = bias[o];
    float* op = out + ((size_t)(b*128 + o))*NN + i*96 + jt*48 + jg*3;
    op[0] = acc[oo][0] + bv;
    op[1] = acc[oo][1] + bv;
    op[2] = acc[oo][2] + bv;
  }
}

/* ---- 1x1 conv 128->64: out[b][cc][n] = sum_c W[cc][c]*X[b][c][n] ---- */
__global__ __launch_bounds__(256) void k_conv(const float* __restrict__ X,
    const float* __restrict__ WG, float* __restrict__ out)
{
  __shared__ __align__(16) float Xs[128*32];   /* [c][32 n] 16KB */
  __shared__ __align__(16) float wt[128*64];   /* [c][cc]   32KB */
  int b  = blockIdx.x / 288;
  int n0 = (blockIdx.x % 288) * 32;
  int t  = threadIdx.x;
  for (int idx = t; idx < 8192; idx += 256) {
    int c = idx >> 6, cc = idx & 63;
    wt[idx] = WG[cc*128 + c];
  }
  for (int idx = t; idx < 1024; idx += 256) {
    int c = idx >> 3, wq = idx & 7;
    ((float4*)Xs)[idx] = *(const float4*)&X[((size_t)(b*128 + c))*NN + n0 + wq*4];
  }
  __syncthreads();
  int n = t & 31, og = t >> 5;
  float acc[8];
  #pragma unroll
  for (int k = 0; k < 8; k++) acc[k] = 0.f;
  for (int c = 0; c < 128; c++) {
    float xv = Xs[(c<<5) + n];
    const float* wrow = wt + (c<<6) + og*8;
    float4 wa = *(const float4*)wrow;
    float4 wb = *(const float4*)(wrow + 4);
    acc[0]+=wa.x*xv; acc[1]+=wa.y*xv; acc[2]+=wa.z*xv; acc[3]+=wa.w*xv;
    acc[4]+=wb.x*xv; acc[5]+=wb.y*xv; acc[6]+=wb.z*xv; acc[7]+=wb.w*xv;
  }
  #pragma unroll
  for (int k = 0; k < 8; k++)
    out[((size_t)(b*64 + og*8 + k))*NN + n0 + n] = acc[k];
}

/* ---- phi path: 2x2 maxpool + transpose + bf16 cast.
   in: tp f32 [b][64][96][96] -> out: phiT bf16 [b][2304 k][64 c]
   (rows of 128B so k_attn can stage with coalesced uint4 loads).
   grid = b*I = 192 blocks; thread (cc=t>>2, jq=t&3) pools 12 J values. ---- */
__global__ __launch_bounds__(256) void k_poolT(const float* __restrict__ in, u16* __restrict__ out)
{
  __shared__ float ps[48*68];    /* [J][cc] pad->68, 12.75KB */
  int blk = blockIdx.x;
  int I = blk % 48, b = blk / 48;
  int t = threadIdx.x;
  int cc = t >> 2, jq = t & 3;
  const float* base = in + ((size_t)(b*64 + cc))*NN + (size_t)(2*I)*96;
  #pragma unroll
  for (int j = 0; j < 12; j++) {
    int J = jq*12 + j;
    const float* p = base + 2*J;
    float2 a = *(const float2*)p;
    float2 c = *(const float2*)(p + 96);
    ps[J*68 + cc] = fmaxf(fmaxf(a.x, a.y), fmaxf(c.x, c.y));
  }
  __syncthreads();
  u32* op = (u32*)out + ((size_t)b*2304 + I*48)*32;   /* 48 rows x 32 u32 */
  for (int idx = t; idx < 1536; idx += 256) {
    int row = idx >> 5, pr = idx & 31;
    op[row*32 + pr] = pkbf(ps[row*68 + 2*pr], ps[row*68 + 2*pr + 1]);
  }
}

/* ---- g path: 2x2 maxpool + bf16 cast (layout preserved).
   in: tp f32 [b][64][96][96] -> out: g bf16 [b][64][2304].
   thread handles a J-pair -> one packed u32 store. grid = 1152. ---- */
__global__ __launch_bounds__(256) void k_poolB(const float* __restrict__ in, u16* __restrict__ out)
{
  int t = blockIdx.x*256 + threadIdx.x;   /* 294912 */
  int pr = t % 24; int r = t / 24;
  int I = r % 48; r /= 48;
  int cc = r & 63, b = r >> 6;
  const float* p = in + ((size_t)(b*64 + cc))*NN + (size_t)(2*I)*96 + 4*pr;
  float4 r0 = *(const float4*)p;
  float4 r1 = *(const float4*)(p + 96);
  float m0 = fmaxf(fmaxf(r0.x, r0.y), fmaxf(r1.x, r1.y));
  float m1 = fmaxf(fmaxf(r0.z, r0.w), fmaxf(r1.z, r1.w));
  ((u32*)out)[((size_t)(b*64 + cc))*1152 + I*24 + pr] = pkbf(m0, m1);
}

/* ---- MFMA flash attention, split-K x2 (bf16 inputs pre-converted).
   grid = b(4) x ks(2) x qtile(144) = 1152 blocks (~4.5/CU, LDS cap 5).
   Block: 64 queries (4 waves x 16), keys [ks*1152, +1152) in chunks of 64.
   LDS u16 map:  phi_T [k 64][72]  @0      (9216 B)
                 g_l   [cc 64][72] @4608   (9216 B)
                 P_l   per wave [16 q][72] @9216+wv*1152
   Staging: 4 coalesced uint4 loads + 4 ds_write_b128 per thread per chunk
   (bf16 conversion hoisted to k_poolT/k_poolB - was 24 scalar loads+32 cvt).
   Outputs UNNORMALIZED partial O to PO[ks], and (m,l) to ML; k_amerge combines. ---- */
__global__ __launch_bounds__(256) void k_attn(const float* __restrict__ TH,
    const u16* __restrict__ PHT, const u16* __restrict__ GB,
    float* __restrict__ PO, float* __restrict__ ML)
{
  __shared__ __align__(16) u16 sm[13824];   /* 27648 B */
  int t = threadIdx.x;
  int lane = t & 63, wv = t >> 6;
  int quad = lane >> 4, l15 = lane & 15;
  int id = blockIdx.x;
  int b   = id / 288;
  int rem = id % 288;
  int ks  = rem / 144;
  int q0  = (rem % 144) * 64;
  int qw  = q0 + wv*16;

  /* theta A-fragments, TEMP pre-scaled: A[q=l15][c=half*32+quad*8+j] */
  bf16x8 afrag[2];
  #pragma unroll
  for (int h = 0; h < 2; h++)
    #pragma unroll
    for (int j = 0; j < 8; j++) {
      float v = TEMPF * TH[((size_t)(b*64 + h*32 + quad*8 + j))*NN + qw + l15];
      afrag[h][j] = (short)f2bf(v);
    }

  f32x4 oacc[4];
  #pragma unroll
  for (int ct = 0; ct < 4; ct++)
    #pragma unroll
    for (int r = 0; r < 4; r++) oacc[ct][r] = 0.f;
  float m_r[4], l_r[4];
  #pragma unroll
  for (int r = 0; r < 4; r++) { m_r[r] = -3.0e38f; l_r[r] = 0.f; }

  int k0end = ks*1152 + 1152;
  for (int k0 = ks*1152; k0 < k0end; k0 += 64) {
    __syncthreads();                       /* prev PV done before overwrite */
    /* stage phi_T[k][c]: 64 rows x 128B, 2 uint4/thread, fully coalesced */
    #pragma unroll
    for (int s = 0; s < 2; s++) {
      int idx = t + s*256;
      int row = idx >> 3, q = idx & 7;
      uint4 v = ((const uint4*)(PHT + ((size_t)(b*2304 + k0 + row))*64))[q];
      *(uint4*)&sm[row*72 + q*8] = v;
    }
    /* stage g[cc][k]: 64 rows x 128B */
    #pragma unroll
    for (int s = 0; s < 2; s++) {
      int idx = t + s*256;
      int row = idx >> 3, q = idx & 7;
      uint4 v = *(const uint4*)(GB + (size_t)(b*64 + row)*2304 + k0 + q*8);
      *(uint4*)&sm[4608 + row*72 + q*8] = v;
    }
    __syncthreads();

    /* QK^T: 4 key-tiles x (2 MFMA over c) -> S[q=quad*4+r][key=kt*16+l15] */
    f32x4 s[4];
    #pragma unroll
    for (int kt = 0; kt < 4; kt++) {
      f32x4 acc;
      #pragma unroll
      for (int r = 0; r < 4; r++) acc[r] = 0.f;
      #pragma unroll
      for (int h = 0; h < 2; h++) {
        bf16x8 bfrag = *(const bf16x8*)&sm[(kt*16 + l15)*72 + h*32 + quad*8];
        acc = __builtin_amdgcn_mfma_f32_16x16x32_bf16(afrag[h], bfrag, acc, 0, 0, 0);
      }
      s[kt] = acc;
    }

    /* online softmax, per row r (q = quad*4+r), reduce over 16 lanes + 4 tiles */
    float al[4];
    #pragma unroll
    for (int r = 0; r < 4; r++) {
      float mx = fmaxf(fmaxf(s[0][r], s[1][r]), fmaxf(s[2][r], s[3][r]));
      #pragma unroll
      for (int d = 1; d < 16; d <<= 1) mx = fmaxf(mx, __shfl_xor(mx, d));
      float mn = fmaxf(m_r[r], mx);
      float a  = __expf(m_r[r] - mn);
      m_r[r] = mn;
      float ps = 0.f;
      #pragma unroll
      for (int kt = 0; kt < 4; kt++) {
        float p = __expf(s[kt][r] - mn);
        s[kt][r] = p; ps += p;
      }
      #pragma unroll
      for (int d = 1; d < 16; d <<= 1) ps += __shfl_xor(ps, d);
      l_r[r] = l_r[r]*a + ps;
      al[r] = a;
    }
    /* P -> per-wave LDS (bf16), rescale O */
    #pragma unroll
    for (int kt = 0; kt < 4; kt++)
      #pragma unroll
      for (int r = 0; r < 4; r++)
        sm[9216 + wv*1152 + (quad*4 + r)*72 + kt*16 + l15] = f2bf(s[kt][r]);
    #pragma unroll
    for (int ct = 0; ct < 4; ct++)
      #pragma unroll
      for (int r = 0; r < 4; r++) oacc[ct][r] *= al[r];

    /* PV: A = P[q=l15][key=h*32+quad*8+j], B = g[key][cc=ct*16+l15] */
    bf16x8 pf[2];
    #pragma unroll
    for (int h = 0; h < 2; h++)
      pf[h] = *(const bf16x8*)&sm[9216 + wv*1152 + l15*72 + h*32 + quad*8];
    #pragma unroll
    for (int ct = 0; ct < 4; ct++)
      #pragma unroll
      for (int h = 0; h < 2; h++) {
        bf16x8 gf = *(const bf16x8*)&sm[4608 + (ct*16 + l15)*72 + h*32 + quad*8];
        oacc[ct] = __builtin_amdgcn_mfma_f32_16x16x32_bf16(pf[h], gf, oacc[ct], 0, 0, 0);
      }
  }

  __syncthreads();   /* all waves done with phi/g/P regions */
  /* m,l per query (one lane per row) */
  if (l15 == 0) {
    #pragma unroll
    for (int r = 0; r < 4; r++) {
      int qg = qw + quad*4 + r;
      ML[(size_t)(ks*4 + b)*9216 + qg]         = m_r[r];
      ML[MLSZ + (size_t)(ks*4 + b)*9216 + qg]  = l_r[r];
    }
  }
  /* raw (unnormalized) O, transposed through LDS for coalesced store */
  float* ol = (float*)sm + wv*1280;      /* [cc 64][20] */
  #pragma unroll
  for (int ct = 0; ct < 4; ct++)
    #pragma unroll
    for (int r = 0; r < 4; r++)
      ol[(ct*16 + l15)*20 + quad*4 + r] = oacc[ct][r];
  __syncthreads();
  const float* orow = ol + lane*20;      /* cc = lane */
  float4 v0 = *(const float4*)(orow);
  float4 v1 = *(const float4*)(orow + 4);
  float4 v2 = *(const float4*)(orow + 8);
  float4 v3 = *(const float4*)(orow + 12);
  float* dst = PO + (size_t)ks*POSZ + ((size_t)(b*64 + lane))*NN + qw;
  *(float4*)(dst)      = v0;
  *(float4*)(dst + 4)  = v1;
  *(float4*)(dst + 8)  = v2;
  *(float4*)(dst + 12) = v3;
}

/* ---- combine 2 split-K partials: O = sum(e^{mi-M} POi) / sum(e^{mi-M} li) ---- */
__global__ __launch_bounds__(256) void k_amerge(const float* __restrict__ PO,
    const float* __restrict__ ML, float* __restrict__ OUT)
{
  int idx = blockIdx.x*256 + threadIdx.x;   /* 589824 float4s */
  size_t flat = (size_t)idx*4;
  int bc = (int)(flat / NN);
  int n  = (int)(flat - (size_t)bc*NN);
  int b  = bc >> 6;
  float4 p0 = *(const float4*)&PO[flat];
  float4 p1 = *(const float4*)&PO[POSZ + flat];
  const float* m0p = ML + (size_t)b*9216 + n;
  const float* m1p = ML + (size_t)(4 + b)*9216 + n;
  const float* l0p = ML + MLSZ + (size_t)b*9216 + n;
  const float* l1p = ML + MLSZ + (size_t)(4 + b)*9216 + n;
  float4 m0 = *(const float4*)m0p, m1 = *(const float4*)m1p;
  float4 l0 = *(const float4*)l0p, l1 = *(const float4*)l1p;
  float4 r;
  {
    float M = fmaxf(m0.x, m1.x); float a0 = __expf(m0.x - M), a1 = __expf(m1.x - M);
    r.x = (a0*p0.x + a1*p1.x) / (a0*l0.x + a1*l1.x);
  }
  {
    float M = fmaxf(m0.y, m1.y); float a0 = __expf(m0.y - M), a1 = __expf(m1.y - M);
    r.y = (a0*p0.y + a1*p1.y) / (a0*l0.y + a1*l1.y);
  }
  {
    float M = fmaxf(m0.z, m1.z); float a0 = __expf(m0.z - M), a1 = __expf(m1.z - M);
    r.z = (a0*p0.z + a1*p1.z) / (a0*l0.z + a1*l1.z);
  }
  {
    float M = fmaxf(m0.w, m1.w); float a0 = __expf(m0.w - M), a1 = __expf(m1.w - M);
    r.w = (a0*p0.w + a1*p1.w) / (a0*l0.w + a1*l1.w);
  }
  *(float4*)&OUT[flat] = r;
}

/* ---- o-projection 64->128, swizzled store into k_up block-own prefixes:
   ofin[b][o][i][j] -> dout[b slab][plane o>>2][2i+((o>>1)&1)][2j+(o&1)] ---- */
__global__ __launch_bounds__(256) void k_oconv(const float* __restrict__ X,
    const float* __restrict__ OW, float* __restrict__ dout)
{
  __shared__ __align__(16) float Xs[64*64];    /* [cc][64 n] 16KB */
  __shared__ __align__(16) float wt[64*128];   /* [cc][o]    32KB */
  int b  = blockIdx.x / 144;
  int n0 = (blockIdx.x % 144) * 64;
  int t  = threadIdx.x;
  for (int idx = t; idx < 8192; idx += 256) {
    int cc = idx >> 7, o = idx & 127;
    wt[idx] = OW[o*64 + cc];
  }
  for (int idx = t; idx < 1024; idx += 256) {
    int cc = idx >> 4, wq = idx & 15;
    ((float4*)Xs)[idx] = *(const float4*)&X[((size_t)(b*64 + cc))*NN + n0 + wq*4];
  }
  __syncthreads();
  int n = t & 63, og = t >> 6;
  float acc[32];
  #pragma unroll
  for (int k = 0; k < 32; k++) acc[k] = 0.f;
  for (int cc = 0; cc < 64; cc++) {
    float xv = Xs[(cc << 6) + n];
    const float* wrow = wt + (cc << 7) + og*32;
    #pragma unroll
    for (int k = 0; k < 32; k++) acc[k] += wrow[k]*xv;
  }
  int ng = n0 + n;
  int i = ng / 96, j = ng - (ng/96)*96;
  #pragma unroll
  for (int k = 0; k < 32; k++) {
    int o = og*32 + k;
    size_t addr = (size_t)b*SLABF + (size_t)(o>>2)*HW
                + (size_t)(2*i + ((o>>1)&1))*192 + 2*j + (o&1);
    dout[addr] = acc[k];
  }
}

/* ---- up convtranspose + bias + gamma*y, f32, in-place (R1 winner, unchanged) ---- */
__global__ __launch_bounds__(256) void k_up(float* __restrict__ dout,
    const float* __restrict__ upw, const float* __restrict__ upb,
    const float* __restrict__ Y, const float* __restrict__ gamma_p)
{
  __shared__ __align__(16) float o_s[128*48];   /* [c][48 j] 24KB */
  int blk = blockIdx.x;
  int jh = blk & 1;
  int r1 = blk >> 1;
  int i = r1 % 96, b = r1 / 96;
  int t = threadIdx.x;
  size_t slab = (size_t)b*SLABF;
  const float* src = dout + slab + (size_t)(2*i)*192 + jh*96;

  for (int idx = t; idx < 6144; idx += 256) {
    int run = idx / 192, rem = idx - run*192;
    int r = rem / 96, cl = rem - r*96;
    float v = src[(size_t)run*HW + r*192 + cl];
    int o = 4*run + 2*r + (cl&1);
    o_s[o*48 + (cl>>1)] = v;
  }
  __syncthreads();

  int op_l = t & 31, jg = t >> 5;
  float gm = *gamma_p;

  for (int oc = 0; oc < 4; oc++) {
    int op = oc*32 + op_l;
    float a0[12], a1[12];
    #pragma unroll
    for (int k = 0; k < 12; k++) { a0[k] = 0.f; a1[k] = 0.f; }

    const float* wp = upw + (size_t)op*4;
    const float* xb = o_s + jg*6;
    for (int c = 0; c < 128; c++) {
      float4 wv = *(const float4*)(wp + (size_t)c*512);
      const float* xp = xb + c*48;
      float2 x01 = *(const float2*)(xp);
      float2 x23 = *(const float2*)(xp + 2);
      float2 x45 = *(const float2*)(xp + 4);
      a0[0] += x01.x*wv.x; a0[1] += x01.x*wv.y; a1[0] += x01.x*wv.z; a1[1] += x01.x*wv.w;
      a0[2] += x01.y*wv.x; a0[3] += x01.y*wv.y; a1[2] += x01.y*wv.z; a1[3] += x01.y*wv.w;
      a0[4] += x23.x*wv.x; a0[5] += x23.x*wv.y; a1[4] += x23.x*wv.z; a1[5] += x23.x*wv.w;
      a0[6] += x23.y*wv.x; a0[7] += x23.y*wv.y; a1[6] += x23.y*wv.z; a1[7] += x23.y*wv.w;
      a0[8] += x45.x*wv.x; a0[9] += x45.x*wv.y; a1[8] += x45.x*wv.z; a1[9] += x45.x*wv.w;
      a0[10]+= x45.y*wv.x; a0[11]+= x45.y*wv.y; a1[10]+= x45.y*wv.z; a1[11]+= x45.y*wv.w;
    }

    float bias = upb[op];
    size_t obase = slab + (size_t)op*HW + (size_t)(2*i)*192 + jh*96 + jg*12;
    float* p0 = dout + obase;
    float* p1 = p0 + 192;
    const float* y0 = Y + obase;
    const float* y1 = y0 + 192;
    #pragma unroll
    for (int q = 0; q < 3; q++) {
      float4 ya = *(const float4*)(y0 + 4*q);
      float4 yb = *(const float4*)(y1 + 4*q);
      *(float4*)(p0 + 4*q) = make_float4(a0[4*q+0]+bias+gm*ya.x, a0[4*q+1]+bias+gm*ya.y,
                                         a0[4*q+2]+bias+gm*ya.z, a0[4*q+3]+bias+gm*ya.w);
      *(float4*)(p1 + 4*q) = make_float4(a1[4*q+0]+bias+gm*yb.x, a1[4*q+1]+bias+gm*yb.y,
                                         a1[4*q+2]+bias+gm*yb.z, a1[4*q+3]+bias+gm*yb.w);
    }
  }
}

extern "C" void kernel_launch(void* const* d_in, const int* in_sizes, int n_in,
                              void* d_out, int out_size, void* d_ws, size_t ws_size,
                              hipStream_t stream) {
  const float* x_in  = (const float*)d_in[0];
  const float* y_in  = (const float*)d_in[1];
  const float* d0w   = (const float*)d_in[2];
  const float* d0b   = (const float*)d_in[3];
  const float* d1w   = (const float*)d_in[4];
  const float* d1b   = (const float*)d_in[5];
  const float* thw   = (const float*)d_in[6];
  const float* phw   = (const float*)d_in[7];
  const float* gw    = (const float*)d_in[8];
  const float* ow    = (const float*)d_in[9];
  const float* upw   = (const float*)d_in[10];
  const float* upb   = (const float*)d_in[11];
  const float* gamma = (const float*)d_in[12];
  float* out = (float*)d_out;

  /* d_ws UNUSED; d_in READ-ONLY; all scratch in d_out (see offset map). */
  k_down  <<<768,  256, 0, stream>>>(x_in, d0w, d0b, out + OFF_X);
  k_down  <<<768,  256, 0, stream>>>(y_in, d1w, d1b, out + OFF_Y);
  k_conv  <<<1152, 256, 0, stream>>>(out + OFF_X, thw, out + OFF_TH);
  k_conv  <<<1152, 256, 0, stream>>>(out + OFF_X, phw, out + OFF_TP);
  k_poolT <<<192,  256, 0, stream>>>(out + OFF_TP, (u16*)(out + OFF_PH));
  k_conv  <<<1152, 256, 0, stream>>>(out + OFF_Y, gw, out + OFF_TP);
  k_poolB <<<1152, 256, 0, stream>>>(out + OFF_TP, (u16*)(out + OFF_G));
  k_attn  <<<1152, 256, 0, stream>>>(out + OFF_TH, (const u16*)(out + OFF_PH),
                                     (const u16*)(out + OFF_G), out + OFF_X, out + OFF_Y);
  k_amerge<<<2304, 256, 0, stream>>>(out + OFF_X, out + OFF_Y, out + OFF_OM);
  k_oconv <<<576,  256, 0, stream>>>(out + OFF_OM, ow, out);
  k_up    <<<768,  256, 0, stream>>>(out, upw, upb, y_in, gamma);
}

// Round 5
// 651.924 us; speedup vs baseline: 1.9187x; 1.0545x over previous
//
#include <hip/hip_runtime.h>
#include <hip/hip_bf16.h>

#define NN    9216      /* 96*96   */
#define MM    2304      /* 48*48   */
#define HW    36864     /* 192*192 */
#define SLABF 4718592   /* f32 per batch slab of output: 128*192*192 */
#define TEMPF 5.0f

/* d_out f32 offsets (scratch; lifetimes verified):
   x    [0        , 4718592)   dead after theta/phi convs; then attn PO partials
   y    [4718592  , 9437184)   dead after g conv; then attn m/l partials
   th   [9437184  , 11796480)  dead after attn
   tp   [11796480 , 14155776)  pre-pool temp, dead after pools
   ph   [14155776 , 14745600)  phiT bf16 [b][2304][64] (uses half region)
   g    [14745600 , 15335424)  g bf16 [b][64][2304]   (uses half region)
   omap [15335424 , 17694720)  merged attn out, read by oconv
   ofin : swizzled into plane-0..31 prefix of each batch slab (race-free k_up)
   Order: attn(writes PO@X, ML@Y) -> amerge(reads PO/ML, writes OM) ->
          oconv(reads OM, writes slab prefixes over X/Y/TH/PH/G) -> up. */
#define OFF_X   0
#define OFF_Y   4718592
#define OFF_TH  9437184
#define OFF_TP  11796480
#define OFF_PH  14155776
#define OFF_G   14745600
#define OFF_OM  15335424
#define POSZ    2359296   /* 4*64*9216: one split's partial O */
#define MLSZ    73728     /* 2*4*9216: m (or l) for both splits */

typedef unsigned short u16;
typedef unsigned int   u32;
typedef __attribute__((ext_vector_type(8))) short bf16x8;
typedef __attribute__((ext_vector_type(4))) float f32x4;

__device__ __forceinline__ u16 f2bf(float f){
  u32 u; __builtin_memcpy(&u,&f,4);
  u32 lsb = (u>>16)&1u; u += 0x7fffu + lsb;   /* RNE */
  return (u16)(u>>16);
}
__device__ __forceinline__ u32 pkbf(float a, float b){
  union { __hip_bfloat162 h; u32 u; } v;
  v.h = __float22bfloat162_rn(make_float2(a,b));
  return v.u;
}

/* ---- down conv k=2 s=2, 128->128, f32, LDS-tiled ----
   R3 retile: thread tile 8o x 3j -> 4o x 6j (same 24 acc, 96 FMA/c).
   Weight loads/c: 8 -> 4, strides {0,2048,4096,6144}B fold into one base
   register + immediates (old 8x2048B spans >13-bit imm -> per-load addr math
   was ~35% of VALU issue). LDS reads: 6x ds_read_b128, compile-time offsets,
   worst 2-way bank aliasing (free). Staging/dbuf/grid unchanged (3 blk/CU). */
__global__ __launch_bounds__(256) void k_down(const float* __restrict__ in,
    const float* __restrict__ w, const float* __restrict__ bias, float* __restrict__ out)
{
  __shared__ __align__(16) float xs[2][6144];   /* [32 c][96 col][2 r] interleaved */
  int blk = blockIdx.x;
  int jt = blk & 1;
  int r1 = blk >> 1;
  int i  = r1 % 96; int b = r1 / 96;
  int t  = threadIdx.x;

  const float* src = in + (size_t)b*128*HW + (size_t)(2*i)*192 + jt*96;

  int cl[3], qq[3];
  #pragma unroll
  for (int k = 0; k < 3; k++) {
    int idx = t + k*256;
    cl[k] = idx / 24;
    qq[k] = idx - cl[k]*24;
  }

  float4 va[3], vb[3];
  #pragma unroll
  for (int k = 0; k < 3; k++) {
    const float* p = src + (size_t)cl[k]*HW + qq[k]*4;
    va[k] = *(const float4*)p;
    vb[k] = *(const float4*)(p + 192);
  }
  #pragma unroll
  for (int k = 0; k < 3; k++) {
    float* d = &xs[0][cl[k]*192 + qq[k]*8];
    *(float4*)d       = make_float4(va[k].x, vb[k].x, va[k].y, vb[k].y);
    *(float4*)(d + 4) = make_float4(va[k].z, vb[k].z, va[k].w, vb[k].w);
  }

  int og = t >> 3, jg = t & 7;       /* 32 og x 4 o ; 8 jg x 6 out cols */
  int o0 = og * 4;
  float acc[4][6];
  #pragma unroll
  for (int oo = 0; oo < 4; oo++)
    #pragma unroll
    for (int jj = 0; jj < 6; jj++) acc[oo][jj] = 0.f;

  const float* wbase = w + (size_t)o0*512;   /* w[o][c][4] */

  for (int ch = 0; ch < 4; ch++) {
    /* issue next chunk's global loads early (hide under compute) */
    if (ch < 3) {
      #pragma unroll
      for (int k = 0; k < 3; k++) {
        const float* p = src + (size_t)((ch+1)*32 + cl[k])*HW + qq[k]*4;
        va[k] = *(const float4*)p;
        vb[k] = *(const float4*)(p + 192);
      }
    }
    __syncthreads();                 /* chunk ch LDS writes visible */

    const float* xb = xs[ch & 1];
    const float* wc = wbase + (ch*32)*4;
    for (int c = 0; c < 32; c++) {
      const float* xp = xb + c*192 + jg*24;
      float4 x0 = *(const float4*)(xp);
      float4 x1 = *(const float4*)(xp + 4);
      float4 x2 = *(const float4*)(xp + 8);
      float4 x3 = *(const float4*)(xp + 12);
      float4 x4 = *(const float4*)(xp + 16);
      float4 x5 = *(const float4*)(xp + 20);
      const float* wp = wc + c*4;
      #pragma unroll
      for (int oo = 0; oo < 4; oo++) {
        float4 wv = *(const float4*)(wp + oo*512);   /* w00 w01 w10 w11 */
        acc[oo][0] += x0.x*wv.x + x0.z*wv.y + x0.y*wv.z + x0.w*wv.w;
        acc[oo][1] += x1.x*wv.x + x1.z*wv.y + x1.y*wv.z + x1.w*wv.w;
        acc[oo][2] += x2.x*wv.x + x2.z*wv.y + x2.y*wv.z + x2.w*wv.w;
        acc[oo][3] += x3.x*wv.x + x3.z*wv.y + x3.y*wv.z + x3.w*wv.w;
        acc[oo][4] += x4.x*wv.x + x4.z*wv.y + x4.y*wv.z + x4.w*wv.w;
        acc[oo][5] += x5.x*wv.x + x5.z*wv.y + x5.y*wv.z + x5.w*wv.w;
      }
    }

    /* write next chunk into the other buffer, after compute (T14 split) */
    if (ch < 3) {
      #pragma unroll
      for (int k = 0; k < 3; k++) {
        float* d = &xs[(ch+1) & 1][cl[k]*192 + qq[k]*8];
        *(float4*)d       = make_float4(va[k].x, vb[k].x, va[k].y, vb[k].y);
        *(float4*)(d + 4) = make_float4(va[k].z, vb[k].z, va[k].w, vb[k].w);
      }
    }
  }

  /* epilogue: out[b][o][i][jt*48 + jg*6 + {0..5}] (8B-aligned float2 stores) */
  #pragma unroll
  for (int oo = 0; oo < 4; oo++) {
    int o = o0 + oo;
    float bv = bias[o];
    float* op = out + ((size_t)(b*128 + o))*NN + i*96 + jt*48 + jg*6;
    *(float2*)(op)     = make_float2(acc[oo][0] + bv, acc[oo][1] + bv);
    *(float2*)(op + 2) = make_float2(acc[oo][2] + bv, acc[oo][3] + bv);
    *(float2*)(op + 4) = make_float2(acc[oo][4] + bv, acc[oo][5] + bv);
  }
}

/* ---- 1x1 conv 128->64: out[b][cc][n] = sum_c W[cc][c]*X[b][c][n] ---- */
__global__ __launch_bounds__(256) void k_conv(const float* __restrict__ X,
    const float* __restrict__ WG, float* __restrict__ out)
{
  __shared__ __align__(16) float Xs[128*32];   /* [c][32 n] 16KB */
  __shared__ __align__(16) float wt[128*64];   /* [c][cc]   32KB */
  int b  = blockIdx.x / 288;
  int n0 = (blockIdx.x % 288) * 32;
  int t  = threadIdx.x;
  for (int idx = t; idx < 8192; idx += 256) {
    int c = idx >> 6, cc = idx & 63;
    wt[idx] = WG[cc*128 + c];
  }
  for (int idx = t; idx < 1024; idx += 256) {
    int c = idx >> 3, wq = idx & 7;
    ((float4*)Xs)[idx] = *(const float4*)&X[((size_t)(b*128 + c))*NN + n0 + wq*4];
  }
  __syncthreads();
  int n = t & 31, og = t >> 5;
  float acc[8];
  #pragma unroll
  for (int k = 0; k < 8; k++) acc[k] = 0.f;
  for (int c = 0; c < 128; c++) {
    float xv = Xs[(c<<5) + n];
    const float* wrow = wt + (c<<6) + og*8;
    float4 wa = *(const float4*)wrow;
    float4 wb = *(const float4*)(wrow + 4);
    acc[0]+=wa.x*xv; acc[1]+=wa.y*xv; acc[2]+=wa.z*xv; acc[3]+=wa.w*xv;
    acc[4]+=wb.x*xv; acc[5]+=wb.y*xv; acc[6]+=wb.z*xv; acc[7]+=wb.w*xv;
  }
  #pragma unroll
  for (int k = 0; k < 8; k++)
    out[((size_t)(b*64 + og*8 + k))*NN + n0 + n] = acc[k];
}

/* ---- phi path: 2x2 maxpool + transpose + bf16 cast.
   in: tp f32 [b][64][96][96] -> out: phiT bf16 [b][2304 k][64 c] ---- */
__global__ __launch_bounds__(256) void k_poolT(const float* __restrict__ in, u16* __restrict__ out)
{
  __shared__ float ps[48*68];    /* [J][cc] pad->68, 12.75KB */
  int blk = blockIdx.x;
  int I = blk % 48, b = blk / 48;
  int t = threadIdx.x;
  int cc = t >> 2, jq = t & 3;
  const float* base = in + ((size_t)(b*64 + cc))*NN + (size_t)(2*I)*96;
  #pragma unroll
  for (int j = 0; j < 12; j++) {
    int J = jq*12 + j;
    const float* p = base + 2*J;
    float2 a = *(const float2*)p;
    float2 c = *(const float2*)(p + 96);
    ps[J*68 + cc] = fmaxf(fmaxf(a.x, a.y), fmaxf(c.x, c.y));
  }
  __syncthreads();
  u32* op = (u32*)out + ((size_t)b*2304 + I*48)*32;   /* 48 rows x 32 u32 */
  for (int idx = t; idx < 1536; idx += 256) {
    int row = idx >> 5, pr = idx & 31;
    op[row*32 + pr] = pkbf(ps[row*68 + 2*pr], ps[row*68 + 2*pr + 1]);
  }
}

/* ---- g path: 2x2 maxpool + bf16 cast (layout preserved).
   in: tp f32 [b][64][96][96] -> out: g bf16 [b][64][2304]. ---- */
__global__ __launch_bounds__(256) void k_poolB(const float* __restrict__ in, u16* __restrict__ out)
{
  int t = blockIdx.x*256 + threadIdx.x;   /* 294912 */
  int pr = t % 24; int r = t / 24;
  int I = r % 48; r /= 48;
  int cc = r & 63, b = r >> 6;
  const float* p = in + ((size_t)(b*64 + cc))*NN + (size_t)(2*I)*96 + 4*pr;
  float4 r0 = *(const float4*)p;
  float4 r1 = *(const float4*)(p + 96);
  float m0 = fmaxf(fmaxf(r0.x, r0.y), fmaxf(r1.x, r1.y));
  float m1 = fmaxf(fmaxf(r0.z, r0.w), fmaxf(r1.z, r1.w));
  ((u32*)out)[((size_t)(b*64 + cc))*1152 + I*24 + pr] = pkbf(m0, m1);
}

/* ---- MFMA flash attention, split-K x2 (bf16 inputs pre-converted).
   grid = b(4) x ks(2) x qtile(144) = 1152 blocks (~4.5/CU, LDS cap 5).
   Outputs UNNORMALIZED partial O to PO[ks], (m,l) to ML; k_amerge combines. ---- */
__global__ __launch_bounds__(256) void k_attn(const float* __restrict__ TH,
    const u16* __restrict__ PHT, const u16* __restrict__ GB,
    float* __restrict__ PO, float* __restrict__ ML)
{
  __shared__ __align__(16) u16 sm[13824];   /* 27648 B */
  int t = threadIdx.x;
  int lane = t & 63, wv = t >> 6;
  int quad = lane >> 4, l15 = lane & 15;
  int id = blockIdx.x;
  int b   = id / 288;
  int rem = id % 288;
  int ks  = rem / 144;
  int q0  = (rem % 144) * 64;
  int qw  = q0 + wv*16;

  /* theta A-fragments, TEMP pre-scaled: A[q=l15][c=half*32+quad*8+j] */
  bf16x8 afrag[2];
  #pragma unroll
  for (int h = 0; h < 2; h++)
    #pragma unroll
    for (int j = 0; j < 8; j++) {
      float v = TEMPF * TH[((size_t)(b*64 + h*32 + quad*8 + j))*NN + qw + l15];
      afrag[h][j] = (short)f2bf(v);
    }

  f32x4 oacc[4];
  #pragma unroll
  for (int ct = 0; ct < 4; ct++)
    #pragma unroll
    for (int r = 0; r < 4; r++) oacc[ct][r] = 0.f;
  float m_r[4], l_r[4];
  #pragma unroll
  for (int r = 0; r < 4; r++) { m_r[r] = -3.0e38f; l_r[r] = 0.f; }

  int k0end = ks*1152 + 1152;
  for (int k0 = ks*1152; k0 < k0end; k0 += 64) {
    __syncthreads();                       /* prev PV done before overwrite */
    /* stage phi_T[k][c]: 64 rows x 128B, 2 uint4/thread, fully coalesced */
    #pragma unroll
    for (int s = 0; s < 2; s++) {
      int idx = t + s*256;
      int row = idx >> 3, q = idx & 7;
      uint4 v = ((const uint4*)(PHT + ((size_t)(b*2304 + k0 + row))*64))[q];
      *(uint4*)&sm[row*72 + q*8] = v;
    }
    /* stage g[cc][k]: 64 rows x 128B */
    #pragma unroll
    for (int s = 0; s < 2; s++) {
      int idx = t + s*256;
      int row = idx >> 3, q = idx & 7;
      uint4 v = *(const uint4*)(GB + (size_t)(b*64 + row)*2304 + k0 + q*8);
      *(uint4*)&sm[4608 + row*72 + q*8] = v;
    }
    __syncthreads();

    /* QK^T: 4 key-tiles x (2 MFMA over c) -> S[q=quad*4+r][key=kt*16+l15] */
    f32x4 s[4];
    #pragma unroll
    for (int kt = 0; kt < 4; kt++) {
      f32x4 acc;
      #pragma unroll
      for (int r = 0; r < 4; r++) acc[r] = 0.f;
      #pragma unroll
      for (int h = 0; h < 2; h++) {
        bf16x8 bfrag = *(const bf16x8*)&sm[(kt*16 + l15)*72 + h*32 + quad*8];
        acc = __builtin_amdgcn_mfma_f32_16x16x32_bf16(afrag[h], bfrag, acc, 0, 0, 0);
      }
      s[kt] = acc;
    }

    /* online softmax, per row r (q = quad*4+r), reduce over 16 lanes + 4 tiles */
    float al[4];
    #pragma unroll
    for (int r = 0; r < 4; r++) {
      float mx = fmaxf(fmaxf(s[0][r], s[1][r]), fmaxf(s[2][r], s[3][r]));
      #pragma unroll
      for (int d = 1; d < 16; d <<= 1) mx = fmaxf(mx, __shfl_xor(mx, d));
      float mn = fmaxf(m_r[r], mx);
      float a  = __expf(m_r[r] - mn);
      m_r[r] = mn;
      float ps = 0.f;
      #pragma unroll
      for (int kt = 0; kt < 4; kt++) {
        float p = __expf(s[kt][r] - mn);
        s[kt][r] = p; ps += p;
      }
      #pragma unroll
      for (int d = 1; d < 16; d <<= 1) ps += __shfl_xor(ps, d);
      l_r[r] = l_r[r]*a + ps;
      al[r] = a;
    }
    /* P -> per-wave LDS (bf16), rescale O */
    #pragma unroll
    for (int kt = 0; kt < 4; kt++)
      #pragma unroll
      for (int r = 0; r < 4; r++)
        sm[9216 + wv*1152 + (quad*4 + r)*72 + kt*16 + l15] = f2bf(s[kt][r]);
    #pragma unroll
    for (int ct = 0; ct < 4; ct++)
      #pragma unroll
      for (int r = 0; r < 4; r++) oacc[ct][r] *= al[r];

    /* PV: A = P[q=l15][key=h*32+quad*8+j], B = g[key][cc=ct*16+l15] */
    bf16x8 pf[2];
    #pragma unroll
    for (int h = 0; h < 2; h++)
      pf[h] = *(const bf16x8*)&sm[9216 + wv*1152 + l15*72 + h*32 + quad*8];
    #pragma unroll
    for (int ct = 0; ct < 4; ct++)
      #pragma unroll
      for (int h = 0; h < 2; h++) {
        bf16x8 gf = *(const bf16x8*)&sm[4608 + (ct*16 + l15)*72 + h*32 + quad*8];
        oacc[ct] = __builtin_amdgcn_mfma_f32_16x16x32_bf16(pf[h], gf, oacc[ct], 0, 0, 0);
      }
  }

  __syncthreads();   /* all waves done with phi/g/P regions */
  /* m,l per query (one lane per row) */
  if (l15 == 0) {
    #pragma unroll
    for (int r = 0; r < 4; r++) {
      int qg = qw + quad*4 + r;
      ML[(size_t)(ks*4 + b)*9216 + qg]         = m_r[r];
      ML[MLSZ + (size_t)(ks*4 + b)*9216 + qg]  = l_r[r];
    }
  }
  /* raw (unnormalized) O, transposed through LDS for coalesced store */
  float* ol = (float*)sm + wv*1280;      /* [cc 64][20] */
  #pragma unroll
  for (int ct = 0; ct < 4; ct++)
    #pragma unroll
    for (int r = 0; r < 4; r++)
      ol[(ct*16 + l15)*20 + quad*4 + r] = oacc[ct][r];
  __syncthreads();
  const float* orow = ol + lane*20;      /* cc = lane */
  float4 v0 = *(const float4*)(orow);
  float4 v1 = *(const float4*)(orow + 4);
  float4 v2 = *(const float4*)(orow + 8);
  float4 v3 = *(const float4*)(orow + 12);
  float* dst = PO + (size_t)ks*POSZ + ((size_t)(b*64 + lane))*NN + qw;
  *(float4*)(dst)      = v0;
  *(float4*)(dst + 4)  = v1;
  *(float4*)(dst + 8)  = v2;
  *(float4*)(dst + 12) = v3;
}

/* ---- combine 2 split-K partials: O = sum(e^{mi-M} POi) / sum(e^{mi-M} li) ---- */
__global__ __launch_bounds__(256) void k_amerge(const float* __restrict__ PO,
    const float* __restrict__ ML, float* __restrict__ OUT)
{
  int idx = blockIdx.x*256 + threadIdx.x;   /* 589824 float4s */
  size_t flat = (size_t)idx*4;
  int bc = (int)(flat / NN);
  int n  = (int)(flat - (size_t)bc*NN);
  int b  = bc >> 6;
  float4 p0 = *(const float4*)&PO[flat];
  float4 p1 = *(const float4*)&PO[POSZ + flat];
  const float* m0p = ML + (size_t)b*9216 + n;
  const float* m1p = ML + (size_t)(4 + b)*9216 + n;
  const float* l0p = ML + MLSZ + (size_t)b*9216 + n;
  const float* l1p = ML + MLSZ + (size_t)(4 + b)*9216 + n;
  float4 m0 = *(const float4*)m0p, m1 = *(const float4*)m1p;
  float4 l0 = *(const float4*)l0p, l1 = *(const float4*)l1p;
  float4 r;
  {
    float M = fmaxf(m0.x, m1.x); float a0 = __expf(m0.x - M), a1 = __expf(m1.x - M);
    r.x = (a0*p0.x + a1*p1.x) / (a0*l0.x + a1*l1.x);
  }
  {
    float M = fmaxf(m0.y, m1.y); float a0 = __expf(m0.y - M), a1 = __expf(m1.y - M);
    r.y = (a0*p0.y + a1*p1.y) / (a0*l0.y + a1*l1.y);
  }
  {
    float M = fmaxf(m0.z, m1.z); float a0 = __expf(m0.z - M), a1 = __expf(m1.z - M);
    r.z = (a0*p0.z + a1*p1.z) / (a0*l0.z + a1*l1.z);
  }
  {
    float M = fmaxf(m0.w, m1.w); float a0 = __expf(m0.w - M), a1 = __expf(m1.w - M);
    r.w = (a0*p0.w + a1*p1.w) / (a0*l0.w + a1*l1.w);
  }
  *(float4*)&OUT[flat] = r;
}

/* ---- o-projection 64->128, swizzled store into k_up block-own prefixes:
   ofin[b][o][i][j] -> dout[b slab][plane o>>2][2i+((o>>1)&1)][2j+(o&1)] ---- */
__global__ __launch_bounds__(256) void k_oconv(const float* __restrict__ X,
    const float* __restrict__ OW, float* __restrict__ dout)
{
  __shared__ __align__(16) float Xs[64*64];    /* [cc][64 n] 16KB */
  __shared__ __align__(16) float wt[64*128];   /* [cc][o]    32KB */
  int b  = blockIdx.x / 144;
  int n0 = (blockIdx.x % 144) * 64;
  int t  = threadIdx.x;
  for (int idx = t; idx < 8192; idx += 256) {
    int cc = idx >> 7, o = idx & 127;
    wt[idx] = OW[o*64 + cc];
  }
  for (int idx = t; idx < 1024; idx += 256) {
    int cc = idx >> 4, wq = idx & 15;
    ((float4*)Xs)[idx] = *(const float4*)&X[((size_t)(b*64 + cc))*NN + n0 + wq*4];
  }
  __syncthreads();
  int n = t & 63, og = t >> 6;
  float acc[32];
  #pragma unroll
  for (int k = 0; k < 32; k++) acc[k] = 0.f;
  for (int cc = 0; cc < 64; cc++) {
    float xv = Xs[(cc << 6) + n];
    const float* wrow = wt + (cc << 7) + og*32;
    #pragma unroll
    for (int k = 0; k < 32; k++) acc[k] += wrow[k]*xv;
  }
  int ng = n0 + n;
  int i = ng / 96, j = ng - (ng/96)*96;
  #pragma unroll
  for (int k = 0; k < 32; k++) {
    int o = og*32 + k;
    size_t addr = (size_t)b*SLABF + (size_t)(o>>2)*HW
                + (size_t)(2*i + ((o>>1)&1))*192 + 2*j + (o&1);
    dout[addr] = acc[k];
  }
}

/* ---- up convtranspose + bias + gamma*y, f32, in-place (R1 winner, unchanged) ---- */
__global__ __launch_bounds__(256) void k_up(float* __restrict__ dout,
    const float* __restrict__ upw, const float* __restrict__ upb,
    const float* __restrict__ Y, const float* __restrict__ gamma_p)
{
  __shared__ __align__(16) float o_s[128*48];   /* [c][48 j] 24KB */
  int blk = blockIdx.x;
  int jh = blk & 1;
  int r1 = blk >> 1;
  int i = r1 % 96, b = r1 / 96;
  int t = threadIdx.x;
  size_t slab = (size_t)b*SLABF;
  const float* src = dout + slab + (size_t)(2*i)*192 + jh*96;

  for (int idx = t; idx < 6144; idx += 256) {
    int run = idx / 192, rem = idx - run*192;
    int r = rem / 96, cl = rem - r*96;
    float v = src[(size_t)run*HW + r*192 + cl];
    int o = 4*run + 2*r + (cl&1);
    o_s[o*48 + (cl>>1)] = v;
  }
  __syncthreads();

  int op_l = t & 31, jg = t >> 5;
  float gm = *gamma_p;

  for (int oc = 0; oc < 4; oc++) {
    int op = oc*32 + op_l;
    float a0[12], a1[12];
    #pragma unroll
    for (int k = 0; k < 12; k++) { a0[k] = 0.f; a1[k] = 0.f; }

    const float* wp = upw + (size_t)op*4;
    const float* xb = o_s + jg*6;
    for (int c = 0; c < 128; c++) {
      float4 wv = *(const float4*)(wp + (size_t)c*512);
      const float* xp = xb + c*48;
      float2 x01 = *(const float2*)(xp);
      float2 x23 = *(const float2*)(xp + 2);
      float2 x45 = *(const float2*)(xp + 4);
      a0[0] += x01.x*wv.x; a0[1] += x01.x*wv.y; a1[0] += x01.x*wv.z; a1[1] += x01.x*wv.w;
      a0[2] += x01.y*wv.x; a0[3] += x01.y*wv.y; a1[2] += x01.y*wv.z; a1[3] += x01.y*wv.w;
      a0[4] += x23.x*wv.x; a0[5] += x23.x*wv.y; a1[4] += x23.x*wv.z; a1[5] += x23.x*wv.w;
      a0[6] += x23.y*wv.x; a0[7] += x23.y*wv.y; a1[6] += x23.y*wv.z; a1[7] += x23.y*wv.w;
      a0[8] += x45.x*wv.x; a0[9] += x45.x*wv.y; a1[8] += x45.x*wv.z; a1[9] += x45.x*wv.w;
      a0[10]+= x45.y*wv.x; a0[11]+= x45.y*wv.y; a1[10]+= x45.y*wv.z; a1[11]+= x45.y*wv.w;
    }

    float bias = upb[op];
    size_t obase = slab + (size_t)op*HW + (size_t)(2*i)*192 + jh*96 + jg*12;
    float* p0 = dout + obase;
    float* p1 = p0 + 192;
    const float* y0 = Y + obase;
    const float* y1 = y0 + 192;
    #pragma unroll
    for (int q = 0; q < 3; q++) {
      float4 ya = *(const float4*)(y0 + 4*q);
      float4 yb = *(const float4*)(y1 + 4*q);
      *(float4*)(p0 + 4*q) = make_float4(a0[4*q+0]+bias+gm*ya.x, a0[4*q+1]+bias+gm*ya.y,
                                         a0[4*q+2]+bias+gm*ya.z, a0[4*q+3]+bias+gm*ya.w);
      *(float4*)(p1 + 4*q) = make_float4(a1[4*q+0]+bias+gm*yb.x, a1[4*q+1]+bias+gm*yb.y,
                                         a1[4*q+2]+bias+gm*yb.z, a1[4*q+3]+bias+gm*yb.w);
    }
  }
}

extern "C" void kernel_launch(void* const* d_in, const int* in_sizes, int n_in,
                              void* d_out, int out_size, void* d_ws, size_t ws_size,
                              hipStream_t stream) {
  const float* x_in  = (const float*)d_in[0];
  const float* y_in  = (const float*)d_in[1];
  const float* d0w   = (const float*)d_in[2];
  const float* d0b   = (const float*)d_in[3];
  const float* d1w   = (const float*)d_in[4];
  const float* d1b   = (const float*)d_in[5];
  const float* thw   = (const float*)d_in[6];
  const float* phw   = (const float*)d_in[7];
  const float* gw    = (const float*)d_in[8];
  const float* ow    = (const float*)d_in[9];
  const float* upw   = (const float*)d_in[10];
  const float* upb   = (const float*)d_in[11];
  const float* gamma = (const float*)d_in[12];
  float* out = (float*)d_out;

  /* d_ws UNUSED; d_in READ-ONLY; all scratch in d_out (see offset map). */
  k_down  <<<768,  256, 0, stream>>>(x_in, d0w, d0b, out + OFF_X);
  k_down  <<<768,  256, 0, stream>>>(y_in, d1w, d1b, out + OFF_Y);
  k_conv  <<<1152, 256, 0, stream>>>(out + OFF_X, thw, out + OFF_TH);
  k_conv  <<<1152, 256, 0, stream>>>(out + OFF_X, phw, out + OFF_TP);
  k_poolT <<<192,  256, 0, stream>>>(out + OFF_TP, (u16*)(out + OFF_PH));
  k_conv  <<<1152, 256, 0, stream>>>(out + OFF_Y, gw, out + OFF_TP);
  k_poolB <<<1152, 256, 0, stream>>>(out + OFF_TP, (u16*)(out + OFF_G));
  k_attn  <<<1152, 256, 0, stream>>>(out + OFF_TH, (const u16*)(out + OFF_PH),
                                     (const u16*)(out + OFF_G), out + OFF_X, out + OFF_Y);
  k_amerge<<<2304, 256, 0, stream>>>(out + OFF_X, out + OFF_Y, out + OFF_OM);
  k_oconv <<<576,  256, 0, stream>>>(out + OFF_OM, ow, out);
  k_up    <<<768,  256, 0, stream>>>(out, upw, upb, y_in, gamma);
}

// Round 6
// 647.746 us; speedup vs baseline: 1.9311x; 1.0065x over previous
//
#include <hip/hip_runtime.h>
#include <hip/hip_bf16.h>

#define NN    9216      /* 96*96   */
#define MM    2304      /* 48*48   */
#define HW    36864     /* 192*192 */
#define SLABF 4718592   /* f32 per batch slab of output: 128*192*192 */
#define TEMPF 5.0f

/* d_out f32 offsets (scratch; lifetimes verified):
   x    [0        , 4718592)   dead after theta/phi convs; then attn PO partials
   y    [4718592  , 9437184)   dead after g conv; then attn m/l partials
   th   [9437184  , 11796480)  dead after attn
   tp   [11796480 , 14155776)  pre-pool temp, dead after pools
   ph   [14155776 , 14745600)  phiT bf16 [b][2304][64] (uses half region)
   g    [14745600 , 15335424)  g bf16 [b][64][2304]   (uses half region)
   omap [15335424 , 17694720)  merged attn out, read by oconv
   ofin : swizzled into plane-0..31 prefix of each batch slab (race-free k_up)
   Order: attn(writes PO@X, ML@Y) -> amerge(reads PO/ML, writes OM) ->
          oconv(reads OM, writes slab prefixes over X/Y/TH/PH/G) -> up. */
#define OFF_X   0
#define OFF_Y   4718592
#define OFF_TH  9437184
#define OFF_TP  11796480
#define OFF_PH  14155776
#define OFF_G   14745600
#define OFF_OM  15335424
#define POSZ    2359296   /* 4*64*9216: one split's partial O */
#define MLSZ    73728     /* 2*4*9216: m (or l) for both splits */

typedef unsigned short u16;
typedef unsigned int   u32;
typedef __attribute__((ext_vector_type(8))) short bf16x8;
typedef __attribute__((ext_vector_type(4))) float f32x4;

__device__ __forceinline__ u16 f2bf(float f){
  u32 u; __builtin_memcpy(&u,&f,4);
  u32 lsb = (u>>16)&1u; u += 0x7fffu + lsb;   /* RNE */
  return (u16)(u>>16);
}
__device__ __forceinline__ u32 pkbf(float a, float b){
  union { __hip_bfloat162 h; u32 u; } v;
  v.h = __float22bfloat162_rn(make_float2(a,b));
  return v.u;
}

/* ---- down conv k=2 s=2, 128->128, f32, LDS-tiled (R3 winner, unchanged) ---- */
__global__ __launch_bounds__(256) void k_down(const float* __restrict__ in,
    const float* __restrict__ w, const float* __restrict__ bias, float* __restrict__ out)
{
  __shared__ __align__(16) float xs[2][6144];   /* [32 c][96 col][2 r] interleaved */
  int blk = blockIdx.x;
  int jt = blk & 1;
  int r1 = blk >> 1;
  int i  = r1 % 96; int b = r1 / 96;
  int t  = threadIdx.x;

  const float* src = in + (size_t)b*128*HW + (size_t)(2*i)*192 + jt*96;

  int cl[3], qq[3];
  #pragma unroll
  for (int k = 0; k < 3; k++) {
    int idx = t + k*256;
    cl[k] = idx / 24;
    qq[k] = idx - cl[k]*24;
  }

  float4 va[3], vb[3];
  #pragma unroll
  for (int k = 0; k < 3; k++) {
    const float* p = src + (size_t)cl[k]*HW + qq[k]*4;
    va[k] = *(const float4*)p;
    vb[k] = *(const float4*)(p + 192);
  }
  #pragma unroll
  for (int k = 0; k < 3; k++) {
    float* d = &xs[0][cl[k]*192 + qq[k]*8];
    *(float4*)d       = make_float4(va[k].x, vb[k].x, va[k].y, vb[k].y);
    *(float4*)(d + 4) = make_float4(va[k].z, vb[k].z, va[k].w, vb[k].w);
  }

  int og = t >> 3, jg = t & 7;       /* 32 og x 4 o ; 8 jg x 6 out cols */
  int o0 = og * 4;
  float acc[4][6];
  #pragma unroll
  for (int oo = 0; oo < 4; oo++)
    #pragma unroll
    for (int jj = 0; jj < 6; jj++) acc[oo][jj] = 0.f;

  const float* wbase = w + (size_t)o0*512;   /* w[o][c][4] */

  for (int ch = 0; ch < 4; ch++) {
    /* issue next chunk's global loads early (hide under compute) */
    if (ch < 3) {
      #pragma unroll
      for (int k = 0; k < 3; k++) {
        const float* p = src + (size_t)((ch+1)*32 + cl[k])*HW + qq[k]*4;
        va[k] = *(const float4*)p;
        vb[k] = *(const float4*)(p + 192);
      }
    }
    __syncthreads();                 /* chunk ch LDS writes visible */

    const float* xb = xs[ch & 1];
    const float* wc = wbase + (ch*32)*4;
    for (int c = 0; c < 32; c++) {
      const float* xp = xb + c*192 + jg*24;
      float4 x0 = *(const float4*)(xp);
      float4 x1 = *(const float4*)(xp + 4);
      float4 x2 = *(const float4*)(xp + 8);
      float4 x3 = *(const float4*)(xp + 12);
      float4 x4 = *(const float4*)(xp + 16);
      float4 x5 = *(const float4*)(xp + 20);
      const float* wp = wc + c*4;
      #pragma unroll
      for (int oo = 0; oo < 4; oo++) {
        float4 wv = *(const float4*)(wp + oo*512);   /* w00 w01 w10 w11 */
        acc[oo][0] += x0.x*wv.x + x0.z*wv.y + x0.y*wv.z + x0.w*wv.w;
        acc[oo][1] += x1.x*wv.x + x1.z*wv.y + x1.y*wv.z + x1.w*wv.w;
        acc[oo][2] += x2.x*wv.x + x2.z*wv.y + x2.y*wv.z + x2.w*wv.w;
        acc[oo][3] += x3.x*wv.x + x3.z*wv.y + x3.y*wv.z + x3.w*wv.w;
        acc[oo][4] += x4.x*wv.x + x4.z*wv.y + x4.y*wv.z + x4.w*wv.w;
        acc[oo][5] += x5.x*wv.x + x5.z*wv.y + x5.y*wv.z + x5.w*wv.w;
      }
    }

    /* write next chunk into the other buffer, after compute (T14 split) */
    if (ch < 3) {
      #pragma unroll
      for (int k = 0; k < 3; k++) {
        float* d = &xs[(ch+1) & 1][cl[k]*192 + qq[k]*8];
        *(float4*)d       = make_float4(va[k].x, vb[k].x, va[k].y, vb[k].y);
        *(float4*)(d + 4) = make_float4(va[k].z, vb[k].z, va[k].w, vb[k].w);
      }
    }
  }

  /* epilogue: out[b][o][i][jt*48 + jg*6 + {0..5}] (8B-aligned float2 stores) */
  #pragma unroll
  for (int oo = 0; oo < 4; oo++) {
    int o = o0 + oo;
    float bv = bias[o];
    float* op = out + ((size_t)(b*128 + o))*NN + i*96 + jt*48 + jg*6;
    *(float2*)(op)     = make_float2(acc[oo][0] + bv, acc[oo][1] + bv);
    *(float2*)(op + 2) = make_float2(acc[oo][2] + bv, acc[oo][3] + bv);
    *(float2*)(op + 4) = make_float2(acc[oo][4] + bv, acc[oo][5] + bv);
  }
}

/* ---- 1x1 conv 128->64: out[b][cc][n] = sum_c W[cc][c]*X[b][c][n] ---- */
__global__ __launch_bounds__(256) void k_conv(const float* __restrict__ X,
    const float* __restrict__ WG, float* __restrict__ out)
{
  __shared__ __align__(16) float Xs[128*32];   /* [c][32 n] 16KB */
  __shared__ __align__(16) float wt[128*64];   /* [c][cc]   32KB */
  int b  = blockIdx.x / 288;
  int n0 = (blockIdx.x % 288) * 32;
  int t  = threadIdx.x;
  for (int idx = t; idx < 8192; idx += 256) {
    int c = idx >> 6, cc = idx & 63;
    wt[idx] = WG[cc*128 + c];
  }
  for (int idx = t; idx < 1024; idx += 256) {
    int c = idx >> 3, wq = idx & 7;
    ((float4*)Xs)[idx] = *(const float4*)&X[((size_t)(b*128 + c))*NN + n0 + wq*4];
  }
  __syncthreads();
  int n = t & 31, og = t >> 5;
  float acc[8];
  #pragma unroll
  for (int k = 0; k < 8; k++) acc[k] = 0.f;
  for (int c = 0; c < 128; c++) {
    float xv = Xs[(c<<5) + n];
    const float* wrow = wt + (c<<6) + og*8;
    float4 wa = *(const float4*)wrow;
    float4 wb = *(const float4*)(wrow + 4);
    acc[0]+=wa.x*xv; acc[1]+=wa.y*xv; acc[2]+=wa.z*xv; acc[3]+=wa.w*xv;
    acc[4]+=wb.x*xv; acc[5]+=wb.y*xv; acc[6]+=wb.z*xv; acc[7]+=wb.w*xv;
  }
  #pragma unroll
  for (int k = 0; k < 8; k++)
    out[((size_t)(b*64 + og*8 + k))*NN + n0 + n] = acc[k];
}

/* ---- phi path: 2x2 maxpool + transpose + bf16 cast.
   in: tp f32 [b][64][96][96] -> out: phiT bf16 [b][2304 k][64 c] ---- */
__global__ __launch_bounds__(256) void k_poolT(const float* __restrict__ in, u16* __restrict__ out)
{
  __shared__ float ps[48*68];    /* [J][cc] pad->68, 12.75KB */
  int blk = blockIdx.x;
  int I = blk % 48, b = blk / 48;
  int t = threadIdx.x;
  int cc = t >> 2, jq = t & 3;
  const float* base = in + ((size_t)(b*64 + cc))*NN + (size_t)(2*I)*96;
  #pragma unroll
  for (int j = 0; j < 12; j++) {
    int J = jq*12 + j;
    const float* p = base + 2*J;
    float2 a = *(const float2*)p;
    float2 c = *(const float2*)(p + 96);
    ps[J*68 + cc] = fmaxf(fmaxf(a.x, a.y), fmaxf(c.x, c.y));
  }
  __syncthreads();
  u32* op = (u32*)out + ((size_t)b*2304 + I*48)*32;   /* 48 rows x 32 u32 */
  for (int idx = t; idx < 1536; idx += 256) {
    int row = idx >> 5, pr = idx & 31;
    op[row*32 + pr] = pkbf(ps[row*68 + 2*pr], ps[row*68 + 2*pr + 1]);
  }
}

/* ---- g path: 2x2 maxpool + bf16 cast (layout preserved).
   in: tp f32 [b][64][96][96] -> out: g bf16 [b][64][2304]. ---- */
__global__ __launch_bounds__(256) void k_poolB(const float* __restrict__ in, u16* __restrict__ out)
{
  int t = blockIdx.x*256 + threadIdx.x;   /* 294912 */
  int pr = t % 24; int r = t / 24;
  int I = r % 48; r /= 48;
  int cc = r & 63, b = r >> 6;
  const float* p = in + ((size_t)(b*64 + cc))*NN + (size_t)(2*I)*96 + 4*pr;
  float4 r0 = *(const float4*)p;
  float4 r1 = *(const float4*)(p + 96);
  float m0 = fmaxf(fmaxf(r0.x, r0.y), fmaxf(r1.x, r1.y));
  float m1 = fmaxf(fmaxf(r0.z, r0.w), fmaxf(r1.z, r1.w));
  ((u32*)out)[((size_t)(b*64 + cc))*1152 + I*24 + pr] = pkbf(m0, m1);
}

/* ---- MFMA flash attention, split-K x2 (bf16 inputs pre-converted).
   grid = b(4) x ks(2) x qtile(144) = 1152 blocks (~4.5/CU, LDS cap 5).
   Outputs UNNORMALIZED partial O to PO[ks], (m,l) to ML; k_amerge combines. ---- */
__global__ __launch_bounds__(256) void k_attn(const float* __restrict__ TH,
    const u16* __restrict__ PHT, const u16* __restrict__ GB,
    float* __restrict__ PO, float* __restrict__ ML)
{
  __shared__ __align__(16) u16 sm[13824];   /* 27648 B */
  int t = threadIdx.x;
  int lane = t & 63, wv = t >> 6;
  int quad = lane >> 4, l15 = lane & 15;
  int id = blockIdx.x;
  int b   = id / 288;
  int rem = id % 288;
  int ks  = rem / 144;
  int q0  = (rem % 144) * 64;
  int qw  = q0 + wv*16;

  /* theta A-fragments, TEMP pre-scaled: A[q=l15][c=half*32+quad*8+j] */
  bf16x8 afrag[2];
  #pragma unroll
  for (int h = 0; h < 2; h++)
    #pragma unroll
    for (int j = 0; j < 8; j++) {
      float v = TEMPF * TH[((size_t)(b*64 + h*32 + quad*8 + j))*NN + qw + l15];
      afrag[h][j] = (short)f2bf(v);
    }

  f32x4 oacc[4];
  #pragma unroll
  for (int ct = 0; ct < 4; ct++)
    #pragma unroll
    for (int r = 0; r < 4; r++) oacc[ct][r] = 0.f;
  float m_r[4], l_r[4];
  #pragma unroll
  for (int r = 0; r < 4; r++) { m_r[r] = -3.0e38f; l_r[r] = 0.f; }

  int k0end = ks*1152 + 1152;
  for (int k0 = ks*1152; k0 < k0end; k0 += 64) {
    __syncthreads();                       /* prev PV done before overwrite */
    /* stage phi_T[k][c]: 64 rows x 128B, 2 uint4/thread, fully coalesced */
    #pragma unroll
    for (int s = 0; s < 2; s++) {
      int idx = t + s*256;
      int row = idx >> 3, q = idx & 7;
      uint4 v = ((const uint4*)(PHT + ((size_t)(b*2304 + k0 + row))*64))[q];
      *(uint4*)&sm[row*72 + q*8] = v;
    }
    /* stage g[cc][k]: 64 rows x 128B */
    #pragma unroll
    for (int s = 0; s < 2; s++) {
      int idx = t + s*256;
      int row = idx >> 3, q = idx & 7;
      uint4 v = *(const uint4*)(GB + (size_t)(b*64 + row)*2304 + k0 + q*8);
      *(uint4*)&sm[4608 + row*72 + q*8] = v;
    }
    __syncthreads();

    /* QK^T: 4 key-tiles x (2 MFMA over c) -> S[q=quad*4+r][key=kt*16+l15] */
    f32x4 s[4];
    #pragma unroll
    for (int kt = 0; kt < 4; kt++) {
      f32x4 acc;
      #pragma unroll
      for (int r = 0; r < 4; r++) acc[r] = 0.f;
      #pragma unroll
      for (int h = 0; h < 2; h++) {
        bf16x8 bfrag = *(const bf16x8*)&sm[(kt*16 + l15)*72 + h*32 + quad*8];
        acc = __builtin_amdgcn_mfma_f32_16x16x32_bf16(afrag[h], bfrag, acc, 0, 0, 0);
      }
      s[kt] = acc;
    }

    /* online softmax, per row r (q = quad*4+r), reduce over 16 lanes + 4 tiles */
    float al[4];
    #pragma unroll
    for (int r = 0; r < 4; r++) {
      float mx = fmaxf(fmaxf(s[0][r], s[1][r]), fmaxf(s[2][r], s[3][r]));
      #pragma unroll
      for (int d = 1; d < 16; d <<= 1) mx = fmaxf(mx, __shfl_xor(mx, d));
      float mn = fmaxf(m_r[r], mx);
      float a  = __expf(m_r[r] - mn);
      m_r[r] = mn;
      float ps = 0.f;
      #pragma unroll
      for (int kt = 0; kt < 4; kt++) {
        float p = __expf(s[kt][r] - mn);
        s[kt][r] = p; ps += p;
      }
      #pragma unroll
      for (int d = 1; d < 16; d <<= 1) ps += __shfl_xor(ps, d);
      l_r[r] = l_r[r]*a + ps;
      al[r] = a;
    }
    /* P -> per-wave LDS (bf16), rescale O */
    #pragma unroll
    for (int kt = 0; kt < 4; kt++)
      #pragma unroll
      for (int r = 0; r < 4; r++)
        sm[9216 + wv*1152 + (quad*4 + r)*72 + kt*16 + l15] = f2bf(s[kt][r]);
    #pragma unroll
    for (int ct = 0; ct < 4; ct++)
      #pragma unroll
      for (int r = 0; r < 4; r++) oacc[ct][r] *= al[r];

    /* PV: A = P[q=l15][key=h*32+quad*8+j], B = g[key][cc=ct*16+l15] */
    bf16x8 pf[2];
    #pragma unroll
    for (int h = 0; h < 2; h++)
      pf[h] = *(const bf16x8*)&sm[9216 + wv*1152 + l15*72 + h*32 + quad*8];
    #pragma unroll
    for (int ct = 0; ct < 4; ct++)
      #pragma unroll
      for (int h = 0; h < 2; h++) {
        bf16x8 gf = *(const bf16x8*)&sm[4608 + (ct*16 + l15)*72 + h*32 + quad*8];
        oacc[ct] = __builtin_amdgcn_mfma_f32_16x16x32_bf16(pf[h], gf, oacc[ct], 0, 0, 0);
      }
  }

  __syncthreads();   /* all waves done with phi/g/P regions */
  /* m,l per query (one lane per row) */
  if (l15 == 0) {
    #pragma unroll
    for (int r = 0; r < 4; r++) {
      int qg = qw + quad*4 + r;
      ML[(size_t)(ks*4 + b)*9216 + qg]         = m_r[r];
      ML[MLSZ + (size_t)(ks*4 + b)*9216 + qg]  = l_r[r];
    }
  }
  /* raw (unnormalized) O, transposed through LDS for coalesced store */
  float* ol = (float*)sm + wv*1280;      /* [cc 64][20] */
  #pragma unroll
  for (int ct = 0; ct < 4; ct++)
    #pragma unroll
    for (int r = 0; r < 4; r++)
      ol[(ct*16 + l15)*20 + quad*4 + r] = oacc[ct][r];
  __syncthreads();
  const float* orow = ol + lane*20;      /* cc = lane */
  float4 v0 = *(const float4*)(orow);
  float4 v1 = *(const float4*)(orow + 4);
  float4 v2 = *(const float4*)(orow + 8);
  float4 v3 = *(const float4*)(orow + 12);
  float* dst = PO + (size_t)ks*POSZ + ((size_t)(b*64 + lane))*NN + qw;
  *(float4*)(dst)      = v0;
  *(float4*)(dst + 4)  = v1;
  *(float4*)(dst + 8)  = v2;
  *(float4*)(dst + 12) = v3;
}

/* ---- combine 2 split-K partials: O = sum(e^{mi-M} POi) / sum(e^{mi-M} li) ---- */
__global__ __launch_bounds__(256) void k_amerge(const float* __restrict__ PO,
    const float* __restrict__ ML, float* __restrict__ OUT)
{
  int idx = blockIdx.x*256 + threadIdx.x;   /* 589824 float4s */
  size_t flat = (size_t)idx*4;
  int bc = (int)(flat / NN);
  int n  = (int)(flat - (size_t)bc*NN);
  int b  = bc >> 6;
  float4 p0 = *(const float4*)&PO[flat];
  float4 p1 = *(const float4*)&PO[POSZ + flat];
  const float* m0p = ML + (size_t)b*9216 + n;
  const float* m1p = ML + (size_t)(4 + b)*9216 + n;
  const float* l0p = ML + MLSZ + (size_t)b*9216 + n;
  const float* l1p = ML + MLSZ + (size_t)(4 + b)*9216 + n;
  float4 m0 = *(const float4*)m0p, m1 = *(const float4*)m1p;
  float4 l0 = *(const float4*)l0p, l1 = *(const float4*)l1p;
  float4 r;
  {
    float M = fmaxf(m0.x, m1.x); float a0 = __expf(m0.x - M), a1 = __expf(m1.x - M);
    r.x = (a0*p0.x + a1*p1.x) / (a0*l0.x + a1*l1.x);
  }
  {
    float M = fmaxf(m0.y, m1.y); float a0 = __expf(m0.y - M), a1 = __expf(m1.y - M);
    r.y = (a0*p0.y + a1*p1.y) / (a0*l0.y + a1*l1.y);
  }
  {
    float M = fmaxf(m0.z, m1.z); float a0 = __expf(m0.z - M), a1 = __expf(m1.z - M);
    r.z = (a0*p0.z + a1*p1.z) / (a0*l0.z + a1*l1.z);
  }
  {
    float M = fmaxf(m0.w, m1.w); float a0 = __expf(m0.w - M), a1 = __expf(m1.w - M);
    r.w = (a0*p0.w + a1*p1.w) / (a0*l0.w + a1*l1.w);
  }
  *(float4*)&OUT[flat] = r;
}

/* ---- o-projection 64->128, swizzled store into k_up block-own prefixes:
   ofin[b][o][i][j] -> dout[b slab][plane o>>2][2i+((o>>1)&1)][2j+(o&1)] ---- */
__global__ __launch_bounds__(256) void k_oconv(const float* __restrict__ X,
    const float* __restrict__ OW, float* __restrict__ dout)
{
  __shared__ __align__(16) float Xs[64*64];    /* [cc][64 n] 16KB */
  __shared__ __align__(16) float wt[64*128];   /* [cc][o]    32KB */
  int b  = blockIdx.x / 144;
  int n0 = (blockIdx.x % 144) * 64;
  int t  = threadIdx.x;
  for (int idx = t; idx < 8192; idx += 256) {
    int cc = idx >> 7, o = idx & 127;
    wt[idx] = OW[o*64 + cc];
  }
  for (int idx = t; idx < 1024; idx += 256) {
    int cc = idx >> 4, wq = idx & 15;
    ((float4*)Xs)[idx] = *(const float4*)&X[((size_t)(b*64 + cc))*NN + n0 + wq*4];
  }
  __syncthreads();
  int n = t & 63, og = t >> 6;
  float acc[32];
  #pragma unroll
  for (int k = 0; k < 32; k++) acc[k] = 0.f;
  for (int cc = 0; cc < 64; cc++) {
    float xv = Xs[(cc << 6) + n];
    const float* wrow = wt + (cc << 7) + og*32;
    #pragma unroll
    for (int k = 0; k < 32; k++) acc[k] += wrow[k]*xv;
  }
  int ng = n0 + n;
  int i = ng / 96, j = ng - (ng/96)*96;
  #pragma unroll
  for (int k = 0; k < 32; k++) {
    int o = og*32 + k;
    size_t addr = (size_t)b*SLABF + (size_t)(o>>2)*HW
                + (size_t)(2*i + ((o>>1)&1))*192 + 2*j + (o&1);
    dout[addr] = acc[k];
  }
}

/* ---- up convtranspose + bias + gamma*y, f32, in-place over d_out. ----
   R5: block = (b, i, jq) jq in 0..3 -> output cols [jq*48,+48), o cols
   [jq*24,+24). LDS 12KB -> 6 blocks/CU, grid 1536 -> 24 waves/CU (75% occ,
   was 3 blk/CU / 30% -> weight-load latency uncovered at 3 waves/SIMD).
   Thread: op_l=t&63 (64 ops/wave, oc-loop=2), jg=t>>6 (6 in-cols).
   Per c: 24 FMA : 1 coalesced 1KB weight read : 3 LDS broadcasts (wave-
   uniform jg -> conflict-free). Race-free: block reads swizzled planes
   0..31 rows 2i,2i+1 cols [jq*48,+48) - subset of what it overwrites. */
__global__ __launch_bounds__(256) void k_up(float* __restrict__ dout,
    const float* __restrict__ upw, const float* __restrict__ upb,
    const float* __restrict__ Y, const float* __restrict__ gamma_p)
{
  __shared__ __align__(16) float o_s[128*24];   /* [c][24 j] 12KB */
  int blk = blockIdx.x;
  int jq = blk & 3;
  int r1 = blk >> 2;
  int i = r1 % 96, b = r1 / 96;
  int t = threadIdx.x;
  size_t slab = (size_t)b*SLABF;
  const float* src = dout + slab + (size_t)(2*i)*192 + jq*48;

  /* phase 0: unswizzle own quarter-prefix -> LDS (32 planes x 2 rows x 48) */
  for (int idx = t; idx < 3072; idx += 256) {
    int run = idx / 96, rem = idx - run*96;
    int r = rem / 48, cl = rem - r*48;
    float v = src[(size_t)run*HW + r*192 + cl];
    int o = 4*run + 2*r + (cl&1);
    o_s[o*24 + (cl>>1)] = v;
  }
  __syncthreads();

  int op_l = t & 63, jg = t >> 6;   /* 64 op-lanes x 4 col-groups of 6 */
  float gm = *gamma_p;

  for (int oc = 0; oc < 2; oc++) {
    int op = oc*64 + op_l;
    float a0[12], a1[12];            /* row 2i / 2i+1, 12 out cols */
    #pragma unroll
    for (int k = 0; k < 12; k++) { a0[k] = 0.f; a1[k] = 0.f; }

    const float* wp = upw + (size_t)op*4;     /* stride 512 f32 per c */
    const float* xb = o_s + jg*6;
    for (int c = 0; c < 128; c++) {
      float4 wv = *(const float4*)(wp + (size_t)c*512);   /* w00 w01 w10 w11 */
      const float* xp = xb + c*24;
      float2 x01 = *(const float2*)(xp);
      float2 x23 = *(const float2*)(xp + 2);
      float2 x45 = *(const float2*)(xp + 4);
      a0[0] += x01.x*wv.x; a0[1] += x01.x*wv.y; a1[0] += x01.x*wv.z; a1[1] += x01.x*wv.w;
      a0[2] += x01.y*wv.x; a0[3] += x01.y*wv.y; a1[2] += x01.y*wv.z; a1[3] += x01.y*wv.w;
      a0[4] += x23.x*wv.x; a0[5] += x23.x*wv.y; a1[4] += x23.x*wv.z; a1[5] += x23.x*wv.w;
      a0[6] += x23.y*wv.x; a0[7] += x23.y*wv.y; a1[6] += x23.y*wv.z; a1[7] += x23.y*wv.w;
      a0[8] += x45.x*wv.x; a0[9] += x45.x*wv.y; a1[8] += x45.x*wv.z; a1[9] += x45.x*wv.w;
      a0[10]+= x45.y*wv.x; a0[11]+= x45.y*wv.y; a1[10]+= x45.y*wv.z; a1[11]+= x45.y*wv.w;
    }

    float bias = upb[op];
    size_t obase = slab + (size_t)op*HW + (size_t)(2*i)*192 + jq*48 + jg*12;
    float* p0 = dout + obase;
    float* p1 = p0 + 192;
    const float* y0 = Y + obase;
    const float* y1 = y0 + 192;
    #pragma unroll
    for (int q = 0; q < 3; q++) {
      float4 ya = *(const float4*)(y0 + 4*q);
      float4 yb = *(const float4*)(y1 + 4*q);
      *(float4*)(p0 + 4*q) = make_float4(a0[4*q+0]+bias+gm*ya.x, a0[4*q+1]+bias+gm*ya.y,
                                         a0[4*q+2]+bias+gm*ya.z, a0[4*q+3]+bias+gm*ya.w);
      *(float4*)(p1 + 4*q) = make_float4(a1[4*q+0]+bias+gm*yb.x, a1[4*q+1]+bias+gm*yb.y,
                                         a1[4*q+2]+bias+gm*yb.z, a1[4*q+3]+bias+gm*yb.w);
    }
  }
}

extern "C" void kernel_launch(void* const* d_in, const int* in_sizes, int n_in,
                              void* d_out, int out_size, void* d_ws, size_t ws_size,
                              hipStream_t stream) {
  const float* x_in  = (const float*)d_in[0];
  const float* y_in  = (const float*)d_in[1];
  const float* d0w   = (const float*)d_in[2];
  const float* d0b   = (const float*)d_in[3];
  const float* d1w   = (const float*)d_in[4];
  const float* d1b   = (const float*)d_in[5];
  const float* thw   = (const float*)d_in[6];
  const float* phw   = (const float*)d_in[7];
  const float* gw    = (const float*)d_in[8];
  const float* ow    = (const float*)d_in[9];
  const float* upw   = (const float*)d_in[10];
  const float* upb   = (const float*)d_in[11];
  const float* gamma = (const float*)d_in[12];
  float* out = (float*)d_out;

  /* d_ws UNUSED; d_in READ-ONLY; all scratch in d_out (see offset map). */
  k_down  <<<768,  256, 0, stream>>>(x_in, d0w, d0b, out + OFF_X);
  k_down  <<<768,  256, 0, stream>>>(y_in, d1w, d1b, out + OFF_Y);
  k_conv  <<<1152, 256, 0, stream>>>(out + OFF_X, thw, out + OFF_TH);
  k_conv  <<<1152, 256, 0, stream>>>(out + OFF_X, phw, out + OFF_TP);
  k_poolT <<<192,  256, 0, stream>>>(out + OFF_TP, (u16*)(out + OFF_PH));
  k_conv  <<<1152, 256, 0, stream>>>(out + OFF_Y, gw, out + OFF_TP);
  k_poolB <<<1152, 256, 0, stream>>>(out + OFF_TP, (u16*)(out + OFF_G));
  k_attn  <<<1152, 256, 0, stream>>>(out + OFF_TH, (const u16*)(out + OFF_PH),
                                     (const u16*)(out + OFF_G), out + OFF_X, out + OFF_Y);
  k_amerge<<<2304, 256, 0, stream>>>(out + OFF_X, out + OFF_Y, out + OFF_OM);
  k_oconv <<<576,  256, 0, stream>>>(out + OFF_OM, ow, out);
  k_up    <<<1536, 256, 0, stream>>>(out, upw, upb, y_in, gamma);
}

// Round 7
// 639.718 us; speedup vs baseline: 1.9553x; 1.0125x over previous
//
#include <hip/hip_runtime.h>
#include <hip/hip_bf16.h>

#define NN    9216      /* 96*96   */
#define MM    2304      /* 48*48   */
#define HW    36864     /* 192*192 */
#define SLABF 4718592   /* f32 per batch slab of output: 128*192*192 */
#define TEMPF 5.0f

/* d_out f32 offsets (scratch; lifetimes verified):
   x    [0        , 4718592)   dead after theta/phi convs; then attn PO partials
   y    [4718592  , 9437184)   dead after g conv; then attn m/l partials
   th   [9437184  , 11796480)  dead after attn
   tp   [11796480 , 14155776)  pre-pool temp, dead after pools
   ph   [14155776 , 14745600)  phiT bf16 [b][2304][64] (uses half region)
   g    [14745600 , 15335424)  g bf16 [b][64][2304]   (uses half region)
   omap [15335424 , 17694720)  merged attn out, read by oconv
   ofin : swizzled into plane-0..31 prefix of each batch slab (race-free k_up)
   Order: attn(writes PO@X, ML@Y) -> amerge(reads PO/ML, writes OM) ->
          oconv(reads OM, writes slab prefixes over X/Y/TH/PH/G) -> up. */
#define OFF_X   0
#define OFF_Y   4718592
#define OFF_TH  9437184
#define OFF_TP  11796480
#define OFF_PH  14155776
#define OFF_G   14745600
#define OFF_OM  15335424
#define POSZ    2359296   /* 4*64*9216: one split's partial O */
#define MLSZ    73728     /* 2*4*9216: m (or l) for both splits */

typedef unsigned short u16;
typedef unsigned int   u32;
typedef __attribute__((ext_vector_type(8))) short bf16x8;
typedef __attribute__((ext_vector_type(4))) float f32x4;

__device__ __forceinline__ u16 f2bf(float f){
  u32 u; __builtin_memcpy(&u,&f,4);
  u32 lsb = (u>>16)&1u; u += 0x7fffu + lsb;   /* RNE */
  return (u16)(u>>16);
}
__device__ __forceinline__ u32 pkbf(float a, float b){
  union { __hip_bfloat162 h; u32 u; } v;
  v.h = __float22bfloat162_rn(make_float2(a,b));
  return v.u;
}

/* ---- down conv k=2 s=2, 128->128, f32, LDS-tiled (R3 winner, unchanged) ---- */
__global__ __launch_bounds__(256) void k_down(const float* __restrict__ in,
    const float* __restrict__ w, const float* __restrict__ bias, float* __restrict__ out)
{
  __shared__ __align__(16) float xs[2][6144];   /* [32 c][96 col][2 r] interleaved */
  int blk = blockIdx.x;
  int jt = blk & 1;
  int r1 = blk >> 1;
  int i  = r1 % 96; int b = r1 / 96;
  int t  = threadIdx.x;

  const float* src = in + (size_t)b*128*HW + (size_t)(2*i)*192 + jt*96;

  int cl[3], qq[3];
  #pragma unroll
  for (int k = 0; k < 3; k++) {
    int idx = t + k*256;
    cl[k] = idx / 24;
    qq[k] = idx - cl[k]*24;
  }

  float4 va[3], vb[3];
  #pragma unroll
  for (int k = 0; k < 3; k++) {
    const float* p = src + (size_t)cl[k]*HW + qq[k]*4;
    va[k] = *(const float4*)p;
    vb[k] = *(const float4*)(p + 192);
  }
  #pragma unroll
  for (int k = 0; k < 3; k++) {
    float* d = &xs[0][cl[k]*192 + qq[k]*8];
    *(float4*)d       = make_float4(va[k].x, vb[k].x, va[k].y, vb[k].y);
    *(float4*)(d + 4) = make_float4(va[k].z, vb[k].z, va[k].w, vb[k].w);
  }

  int og = t >> 3, jg = t & 7;       /* 32 og x 4 o ; 8 jg x 6 out cols */
  int o0 = og * 4;
  float acc[4][6];
  #pragma unroll
  for (int oo = 0; oo < 4; oo++)
    #pragma unroll
    for (int jj = 0; jj < 6; jj++) acc[oo][jj] = 0.f;

  const float* wbase = w + (size_t)o0*512;   /* w[o][c][4] */

  for (int ch = 0; ch < 4; ch++) {
    /* issue next chunk's global loads early (hide under compute) */
    if (ch < 3) {
      #pragma unroll
      for (int k = 0; k < 3; k++) {
        const float* p = src + (size_t)((ch+1)*32 + cl[k])*HW + qq[k]*4;
        va[k] = *(const float4*)p;
        vb[k] = *(const float4*)(p + 192);
      }
    }
    __syncthreads();                 /* chunk ch LDS writes visible */

    const float* xb = xs[ch & 1];
    const float* wc = wbase + (ch*32)*4;
    for (int c = 0; c < 32; c++) {
      const float* xp = xb + c*192 + jg*24;
      float4 x0 = *(const float4*)(xp);
      float4 x1 = *(const float4*)(xp + 4);
      float4 x2 = *(const float4*)(xp + 8);
      float4 x3 = *(const float4*)(xp + 12);
      float4 x4 = *(const float4*)(xp + 16);
      float4 x5 = *(const float4*)(xp + 20);
      const float* wp = wc + c*4;
      #pragma unroll
      for (int oo = 0; oo < 4; oo++) {
        float4 wv = *(const float4*)(wp + oo*512);   /* w00 w01 w10 w11 */
        acc[oo][0] += x0.x*wv.x + x0.z*wv.y + x0.y*wv.z + x0.w*wv.w;
        acc[oo][1] += x1.x*wv.x + x1.z*wv.y + x1.y*wv.z + x1.w*wv.w;
        acc[oo][2] += x2.x*wv.x + x2.z*wv.y + x2.y*wv.z + x2.w*wv.w;
        acc[oo][3] += x3.x*wv.x + x3.z*wv.y + x3.y*wv.z + x3.w*wv.w;
        acc[oo][4] += x4.x*wv.x + x4.z*wv.y + x4.y*wv.z + x4.w*wv.w;
        acc[oo][5] += x5.x*wv.x + x5.z*wv.y + x5.y*wv.z + x5.w*wv.w;
      }
    }

    /* write next chunk into the other buffer, after compute (T14 split) */
    if (ch < 3) {
      #pragma unroll
      for (int k = 0; k < 3; k++) {
        float* d = &xs[(ch+1) & 1][cl[k]*192 + qq[k]*8];
        *(float4*)d       = make_float4(va[k].x, vb[k].x, va[k].y, vb[k].y);
        *(float4*)(d + 4) = make_float4(va[k].z, vb[k].z, va[k].w, vb[k].w);
      }
    }
  }

  /* epilogue: out[b][o][i][jt*48 + jg*6 + {0..5}] (8B-aligned float2 stores) */
  #pragma unroll
  for (int oo = 0; oo < 4; oo++) {
    int o = o0 + oo;
    float bv = bias[o];
    float* op = out + ((size_t)(b*128 + o))*NN + i*96 + jt*48 + jg*6;
    *(float2*)(op)     = make_float2(acc[oo][0] + bv, acc[oo][1] + bv);
    *(float2*)(op + 2) = make_float2(acc[oo][2] + bv, acc[oo][3] + bv);
    *(float2*)(op + 4) = make_float2(acc[oo][4] + bv, acc[oo][5] + bv);
  }
}

/* ---- 1x1 conv 128->64: out[b][cc][n] = sum_c W[cc][c]*X[b][c][n] ---- */
__global__ __launch_bounds__(256) void k_conv(const float* __restrict__ X,
    const float* __restrict__ WG, float* __restrict__ out)
{
  __shared__ __align__(16) float Xs[128*32];   /* [c][32 n] 16KB */
  __shared__ __align__(16) float wt[128*64];   /* [c][cc]   32KB */
  int b  = blockIdx.x / 288;
  int n0 = (blockIdx.x % 288) * 32;
  int t  = threadIdx.x;
  for (int idx = t; idx < 8192; idx += 256) {
    int c = idx >> 6, cc = idx & 63;
    wt[idx] = WG[cc*128 + c];
  }
  for (int idx = t; idx < 1024; idx += 256) {
    int c = idx >> 3, wq = idx & 7;
    ((float4*)Xs)[idx] = *(const float4*)&X[((size_t)(b*128 + c))*NN + n0 + wq*4];
  }
  __syncthreads();
  int n = t & 31, og = t >> 5;
  float acc[8];
  #pragma unroll
  for (int k = 0; k < 8; k++) acc[k] = 0.f;
  for (int c = 0; c < 128; c++) {
    float xv = Xs[(c<<5) + n];
    const float* wrow = wt + (c<<6) + og*8;
    float4 wa = *(const float4*)wrow;
    float4 wb = *(const float4*)(wrow + 4);
    acc[0]+=wa.x*xv; acc[1]+=wa.y*xv; acc[2]+=wa.z*xv; acc[3]+=wa.w*xv;
    acc[4]+=wb.x*xv; acc[5]+=wb.y*xv; acc[6]+=wb.z*xv; acc[7]+=wb.w*xv;
  }
  #pragma unroll
  for (int k = 0; k < 8; k++)
    out[((size_t)(b*64 + og*8 + k))*NN + n0 + n] = acc[k];
}

/* ---- phi path: 2x2 maxpool + transpose + bf16 cast.
   in: tp f32 [b][64][96][96] -> out: phiT bf16 [b][2304 k][64 c] ---- */
__global__ __launch_bounds__(256) void k_poolT(const float* __restrict__ in, u16* __restrict__ out)
{
  __shared__ float ps[48*68];    /* [J][cc] pad->68, 12.75KB */
  int blk = blockIdx.x;
  int I = blk % 48, b = blk / 48;
  int t = threadIdx.x;
  int cc = t >> 2, jq = t & 3;
  const float* base = in + ((size_t)(b*64 + cc))*NN + (size_t)(2*I)*96;
  #pragma unroll
  for (int j = 0; j < 12; j++) {
    int J = jq*12 + j;
    const float* p = base + 2*J;
    float2 a = *(const float2*)p;
    float2 c = *(const float2*)(p + 96);
    ps[J*68 + cc] = fmaxf(fmaxf(a.x, a.y), fmaxf(c.x, c.y));
  }
  __syncthreads();
  u32* op = (u32*)out + ((size_t)b*2304 + I*48)*32;   /* 48 rows x 32 u32 */
  for (int idx = t; idx < 1536; idx += 256) {
    int row = idx >> 5, pr = idx & 31;
    op[row*32 + pr] = pkbf(ps[row*68 + 2*pr], ps[row*68 + 2*pr + 1]);
  }
}

/* ---- g path: 2x2 maxpool + bf16 cast (layout preserved).
   in: tp f32 [b][64][96][96] -> out: g bf16 [b][64][2304]. ---- */
__global__ __launch_bounds__(256) void k_poolB(const float* __restrict__ in, u16* __restrict__ out)
{
  int t = blockIdx.x*256 + threadIdx.x;   /* 294912 */
  int pr = t % 24; int r = t / 24;
  int I = r % 48; r /= 48;
  int cc = r & 63, b = r >> 6;
  const float* p = in + ((size_t)(b*64 + cc))*NN + (size_t)(2*I)*96 + 4*pr;
  float4 r0 = *(const float4*)p;
  float4 r1 = *(const float4*)(p + 96);
  float m0 = fmaxf(fmaxf(r0.x, r0.y), fmaxf(r1.x, r1.y));
  float m1 = fmaxf(fmaxf(r0.z, r0.w), fmaxf(r1.z, r1.w));
  ((u32*)out)[((size_t)(b*64 + cc))*1152 + I*24 + pr] = pkbf(m0, m1);
}

/* ---- MFMA flash attention, split-K x2 (bf16 inputs pre-converted).
   grid = b(4) x ks(2) x qtile(144) = 1152 blocks (~4.5/CU, LDS cap 5).
   Outputs UNNORMALIZED partial O to PO[ks], (m,l) to ML; k_amerge combines. ---- */
__global__ __launch_bounds__(256) void k_attn(const float* __restrict__ TH,
    const u16* __restrict__ PHT, const u16* __restrict__ GB,
    float* __restrict__ PO, float* __restrict__ ML)
{
  __shared__ __align__(16) u16 sm[13824];   /* 27648 B */
  int t = threadIdx.x;
  int lane = t & 63, wv = t >> 6;
  int quad = lane >> 4, l15 = lane & 15;
  int id = blockIdx.x;
  int b   = id / 288;
  int rem = id % 288;
  int ks  = rem / 144;
  int q0  = (rem % 144) * 64;
  int qw  = q0 + wv*16;

  /* theta A-fragments, TEMP pre-scaled: A[q=l15][c=half*32+quad*8+j] */
  bf16x8 afrag[2];
  #pragma unroll
  for (int h = 0; h < 2; h++)
    #pragma unroll
    for (int j = 0; j < 8; j++) {
      float v = TEMPF * TH[((size_t)(b*64 + h*32 + quad*8 + j))*NN + qw + l15];
      afrag[h][j] = (short)f2bf(v);
    }

  f32x4 oacc[4];
  #pragma unroll
  for (int ct = 0; ct < 4; ct++)
    #pragma unroll
    for (int r = 0; r < 4; r++) oacc[ct][r] = 0.f;
  float m_r[4], l_r[4];
  #pragma unroll
  for (int r = 0; r < 4; r++) { m_r[r] = -3.0e38f; l_r[r] = 0.f; }

  int k0end = ks*1152 + 1152;
  for (int k0 = ks*1152; k0 < k0end; k0 += 64) {
    __syncthreads();                       /* prev PV done before overwrite */
    /* stage phi_T[k][c]: 64 rows x 128B, 2 uint4/thread, fully coalesced */
    #pragma unroll
    for (int s = 0; s < 2; s++) {
      int idx = t + s*256;
      int row = idx >> 3, q = idx & 7;
      uint4 v = ((const uint4*)(PHT + ((size_t)(b*2304 + k0 + row))*64))[q];
      *(uint4*)&sm[row*72 + q*8] = v;
    }
    /* stage g[cc][k]: 64 rows x 128B */
    #pragma unroll
    for (int s = 0; s < 2; s++) {
      int idx = t + s*256;
      int row = idx >> 3, q = idx & 7;
      uint4 v = *(const uint4*)(GB + (size_t)(b*64 + row)*2304 + k0 + q*8);
      *(uint4*)&sm[4608 + row*72 + q*8] = v;
    }
    __syncthreads();

    /* QK^T: 4 key-tiles x (2 MFMA over c) -> S[q=quad*4+r][key=kt*16+l15] */
    f32x4 s[4];
    #pragma unroll
    for (int kt = 0; kt < 4; kt++) {
      f32x4 acc;
      #pragma unroll
      for (int r = 0; r < 4; r++) acc[r] = 0.f;
      #pragma unroll
      for (int h = 0; h < 2; h++) {
        bf16x8 bfrag = *(const bf16x8*)&sm[(kt*16 + l15)*72 + h*32 + quad*8];
        acc = __builtin_amdgcn_mfma_f32_16x16x32_bf16(afrag[h], bfrag, acc, 0, 0, 0);
      }
      s[kt] = acc;
    }

    /* online softmax, per row r (q = quad*4+r), reduce over 16 lanes + 4 tiles */
    float al[4];
    #pragma unroll
    for (int r = 0; r < 4; r++) {
      float mx = fmaxf(fmaxf(s[0][r], s[1][r]), fmaxf(s[2][r], s[3][r]));
      #pragma unroll
      for (int d = 1; d < 16; d <<= 1) mx = fmaxf(mx, __shfl_xor(mx, d));
      float mn = fmaxf(m_r[r], mx);
      float a  = __expf(m_r[r] - mn);
      m_r[r] = mn;
      float ps = 0.f;
      #pragma unroll
      for (int kt = 0; kt < 4; kt++) {
        float p = __expf(s[kt][r] - mn);
        s[kt][r] = p; ps += p;
      }
      #pragma unroll
      for (int d = 1; d < 16; d <<= 1) ps += __shfl_xor(ps, d);
      l_r[r] = l_r[r]*a + ps;
      al[r] = a;
    }
    /* P -> per-wave LDS (bf16), rescale O */
    #pragma unroll
    for (int kt = 0; kt < 4; kt++)
      #pragma unroll
      for (int r = 0; r < 4; r++)
        sm[9216 + wv*1152 + (quad*4 + r)*72 + kt*16 + l15] = f2bf(s[kt][r]);
    #pragma unroll
    for (int ct = 0; ct < 4; ct++)
      #pragma unroll
      for (int r = 0; r < 4; r++) oacc[ct][r] *= al[r];

    /* PV: A = P[q=l15][key=h*32+quad*8+j], B = g[key][cc=ct*16+l15] */
    bf16x8 pf[2];
    #pragma unroll
    for (int h = 0; h < 2; h++)
      pf[h] = *(const bf16x8*)&sm[9216 + wv*1152 + l15*72 + h*32 + quad*8];
    #pragma unroll
    for (int ct = 0; ct < 4; ct++)
      #pragma unroll
      for (int h = 0; h < 2; h++) {
        bf16x8 gf = *(const bf16x8*)&sm[4608 + (ct*16 + l15)*72 + h*32 + quad*8];
        oacc[ct] = __builtin_amdgcn_mfma_f32_16x16x32_bf16(pf[h], gf, oacc[ct], 0, 0, 0);
      }
  }

  __syncthreads();   /* all waves done with phi/g/P regions */
  /* m,l per query (one lane per row) */
  if (l15 == 0) {
    #pragma unroll
    for (int r = 0; r < 4; r++) {
      int qg = qw + quad*4 + r;
      ML[(size_t)(ks*4 + b)*9216 + qg]         = m_r[r];
      ML[MLSZ + (size_t)(ks*4 + b)*9216 + qg]  = l_r[r];
    }
  }
  /* raw (unnormalized) O, transposed through LDS for coalesced store */
  float* ol = (float*)sm + wv*1280;      /* [cc 64][20] */
  #pragma unroll
  for (int ct = 0; ct < 4; ct++)
    #pragma unroll
    for (int r = 0; r < 4; r++)
      ol[(ct*16 + l15)*20 + quad*4 + r] = oacc[ct][r];
  __syncthreads();
  const float* orow = ol + lane*20;      /* cc = lane */
  float4 v0 = *(const float4*)(orow);
  float4 v1 = *(const float4*)(orow + 4);
  float4 v2 = *(const float4*)(orow + 8);
  float4 v3 = *(const float4*)(orow + 12);
  float* dst = PO + (size_t)ks*POSZ + ((size_t)(b*64 + lane))*NN + qw;
  *(float4*)(dst)      = v0;
  *(float4*)(dst + 4)  = v1;
  *(float4*)(dst + 8)  = v2;
  *(float4*)(dst + 12) = v3;
}

/* ---- combine 2 split-K partials: O = sum(e^{mi-M} POi) / sum(e^{mi-M} li) ---- */
__global__ __launch_bounds__(256) void k_amerge(const float* __restrict__ PO,
    const float* __restrict__ ML, float* __restrict__ OUT)
{
  int idx = blockIdx.x*256 + threadIdx.x;   /* 589824 float4s */
  size_t flat = (size_t)idx*4;
  int bc = (int)(flat / NN);
  int n  = (int)(flat - (size_t)bc*NN);
  int b  = bc >> 6;
  float4 p0 = *(const float4*)&PO[flat];
  float4 p1 = *(const float4*)&PO[POSZ + flat];
  const float* m0p = ML + (size_t)b*9216 + n;
  const float* m1p = ML + (size_t)(4 + b)*9216 + n;
  const float* l0p = ML + MLSZ + (size_t)b*9216 + n;
  const float* l1p = ML + MLSZ + (size_t)(4 + b)*9216 + n;
  float4 m0 = *(const float4*)m0p, m1 = *(const float4*)m1p;
  float4 l0 = *(const float4*)l0p, l1 = *(const float4*)l1p;
  float4 r;
  {
    float M = fmaxf(m0.x, m1.x); float a0 = __expf(m0.x - M), a1 = __expf(m1.x - M);
    r.x = (a0*p0.x + a1*p1.x) / (a0*l0.x + a1*l1.x);
  }
  {
    float M = fmaxf(m0.y, m1.y); float a0 = __expf(m0.y - M), a1 = __expf(m1.y - M);
    r.y = (a0*p0.y + a1*p1.y) / (a0*l0.y + a1*l1.y);
  }
  {
    float M = fmaxf(m0.z, m1.z); float a0 = __expf(m0.z - M), a1 = __expf(m1.z - M);
    r.z = (a0*p0.z + a1*p1.z) / (a0*l0.z + a1*l1.z);
  }
  {
    float M = fmaxf(m0.w, m1.w); float a0 = __expf(m0.w - M), a1 = __expf(m1.w - M);
    r.w = (a0*p0.w + a1*p1.w) / (a0*l0.w + a1*l1.w);
  }
  *(float4*)&OUT[flat] = r;
}

/* ---- o-projection 64->128, swizzled store into k_up block-own prefixes:
   ofin[b][o][i][j] -> dout[b slab][plane o>>2][2i+((o>>1)&1)][2j+(o&1)] ---- */
__global__ __launch_bounds__(256) void k_oconv(const float* __restrict__ X,
    const float* __restrict__ OW, float* __restrict__ dout)
{
  __shared__ __align__(16) float Xs[64*64];    /* [cc][64 n] 16KB */
  __shared__ __align__(16) float wt[64*128];   /* [cc][o]    32KB */
  int b  = blockIdx.x / 144;
  int n0 = (blockIdx.x % 144) * 64;
  int t  = threadIdx.x;
  for (int idx = t; idx < 8192; idx += 256) {
    int cc = idx >> 7, o = idx & 127;
    wt[idx] = OW[o*64 + cc];
  }
  for (int idx = t; idx < 1024; idx += 256) {
    int cc = idx >> 4, wq = idx & 15;
    ((float4*)Xs)[idx] = *(const float4*)&X[((size_t)(b*64 + cc))*NN + n0 + wq*4];
  }
  __syncthreads();
  int n = t & 63, og = t >> 6;
  float acc[32];
  #pragma unroll
  for (int k = 0; k < 32; k++) acc[k] = 0.f;
  for (int cc = 0; cc < 64; cc++) {
    float xv = Xs[(cc << 6) + n];
    const float* wrow = wt + (cc << 7) + og*32;
    #pragma unroll
    for (int k = 0; k < 32; k++) acc[k] += wrow[k]*xv;
  }
  int ng = n0 + n;
  int i = ng / 96, j = ng - (ng/96)*96;
  #pragma unroll
  for (int k = 0; k < 32; k++) {
    int o = og*32 + k;
    size_t addr = (size_t)b*SLABF + (size_t)(o>>2)*HW
                + (size_t)(2*i + ((o>>1)&1))*192 + 2*j + (o&1);
    dout[addr] = acc[k];
  }
}

/* ---- up convtranspose + bias + gamma*y, f32, in-place over d_out. ----
   R6: wave-role remap to dedupe weight L2 traffic. R5's waves differed only
   in jg -> each of 4 waves streamed the SAME 256KB weight slice (6.3MB/CU of
   L2 reads ~ 46us > 31us FMA floor; why occupancy didn't help in R5).
   Now: wave wv owns ops [wv*32,+32); lane = (op_l 32) x (h6 2 in-col halves).
   Thread: 1 op x 12 in-cols = 48 acc, 48 FMA per 16B weight load.
   Weight stream/wave: 128c x 512B = 64KB (4.2x cut -> 1.5MB/CU ~ 11us).
   x-reads: 3 ds_read_b128 broadcasts per c. Block/grid/LDS/race unchanged. */
__global__ __launch_bounds__(256) void k_up(float* __restrict__ dout,
    const float* __restrict__ upw, const float* __restrict__ upb,
    const float* __restrict__ Y, const float* __restrict__ gamma_p)
{
  __shared__ __align__(16) float o_s[128*24];   /* [c][24 j] 12KB */
  int blk = blockIdx.x;
  int jq = blk & 3;
  int r1 = blk >> 2;
  int i = r1 % 96, b = r1 / 96;
  int t = threadIdx.x;
  size_t slab = (size_t)b*SLABF;
  const float* src = dout + slab + (size_t)(2*i)*192 + jq*48;

  /* phase 0: unswizzle own quarter-prefix -> LDS (32 planes x 2 rows x 48) */
  for (int idx = t; idx < 3072; idx += 256) {
    int run = idx / 96, rem = idx - run*96;
    int r = rem / 48, cl = rem - r*48;
    float v = src[(size_t)run*HW + r*192 + cl];
    int o = 4*run + 2*r + (cl&1);
    o_s[o*24 + (cl>>1)] = v;
  }
  __syncthreads();

  int wv = t >> 6, lane = t & 63;
  int op = wv*32 + (lane & 31);     /* wave owns a 32-op band */
  int h6 = lane >> 5;               /* in-col half: [h6*12, +12) */
  float gm = *gamma_p;

  float a0[24], a1[24];             /* rows 2i / 2i+1, 24 out cols */
  #pragma unroll
  for (int k = 0; k < 24; k++) { a0[k] = 0.f; a1[k] = 0.f; }

  const float* wp = upw + (size_t)op*4;     /* stride 512 f32 per c */
  const float* xb = o_s + h6*12;
  for (int c = 0; c < 128; c++) {
    float4 wv4 = *(const float4*)(wp + (size_t)c*512);   /* w00 w01 w10 w11 */
    const float* xp = xb + c*24;
    float xv[12];
    *(float4*)&xv[0] = *(const float4*)(xp);
    *(float4*)&xv[4] = *(const float4*)(xp + 4);
    *(float4*)&xv[8] = *(const float4*)(xp + 8);
    #pragma unroll
    for (int m = 0; m < 12; m++) {
      a0[2*m]   += xv[m]*wv4.x;
      a0[2*m+1] += xv[m]*wv4.y;
      a1[2*m]   += xv[m]*wv4.z;
      a1[2*m+1] += xv[m]*wv4.w;
    }
  }

  float bias = upb[op];
  size_t obase = slab + (size_t)op*HW + (size_t)(2*i)*192 + jq*48 + h6*24;
  float* p0 = dout + obase;
  float* p1 = p0 + 192;
  const float* y0 = Y + obase;
  const float* y1 = y0 + 192;
  #pragma unroll
  for (int q = 0; q < 6; q++) {
    float4 ya = *(const float4*)(y0 + 4*q);
    float4 yb = *(const float4*)(y1 + 4*q);
    *(float4*)(p0 + 4*q) = make_float4(a0[4*q+0]+bias+gm*ya.x, a0[4*q+1]+bias+gm*ya.y,
                                       a0[4*q+2]+bias+gm*ya.z, a0[4*q+3]+bias+gm*ya.w);
    *(float4*)(p1 + 4*q) = make_float4(a1[4*q+0]+bias+gm*yb.x, a1[4*q+1]+bias+gm*yb.y,
                                       a1[4*q+2]+bias+gm*yb.z, a1[4*q+3]+bias+gm*yb.w);
  }
}

extern "C" void kernel_launch(void* const* d_in, const int* in_sizes, int n_in,
                              void* d_out, int out_size, void* d_ws, size_t ws_size,
                              hipStream_t stream) {
  const float* x_in  = (const float*)d_in[0];
  const float* y_in  = (const float*)d_in[1];
  const float* d0w   = (const float*)d_in[2];
  const float* d0b   = (const float*)d_in[3];
  const float* d1w   = (const float*)d_in[4];
  const float* d1b   = (const float*)d_in[5];
  const float* thw   = (const float*)d_in[6];
  const float* phw   = (const float*)d_in[7];
  const float* gw    = (const float*)d_in[8];
  const float* ow    = (const float*)d_in[9];
  const float* upw   = (const float*)d_in[10];
  const float* upb   = (const float*)d_in[11];
  const float* gamma = (const float*)d_in[12];
  float* out = (float*)d_out;

  /* d_ws UNUSED; d_in READ-ONLY; all scratch in d_out (see offset map). */
  k_down  <<<768,  256, 0, stream>>>(x_in, d0w, d0b, out + OFF_X);
  k_down  <<<768,  256, 0, stream>>>(y_in, d1w, d1b, out + OFF_Y);
  k_conv  <<<1152, 256, 0, stream>>>(out + OFF_X, thw, out + OFF_TH);
  k_conv  <<<1152, 256, 0, stream>>>(out + OFF_X, phw, out + OFF_TP);
  k_poolT <<<192,  256, 0, stream>>>(out + OFF_TP, (u16*)(out + OFF_PH));
  k_conv  <<<1152, 256, 0, stream>>>(out + OFF_Y, gw, out + OFF_TP);
  k_poolB <<<1152, 256, 0, stream>>>(out + OFF_TP, (u16*)(out + OFF_G));
  k_attn  <<<1152, 256, 0, stream>>>(out + OFF_TH, (const u16*)(out + OFF_PH),
                                     (const u16*)(out + OFF_G), out + OFF_X, out + OFF_Y);
  k_amerge<<<2304, 256, 0, stream>>>(out + OFF_X, out + OFF_Y, out + OFF_OM);
  k_oconv <<<576,  256, 0, stream>>>(out + OFF_OM, ow, out);
  k_up    <<<1536, 256, 0, stream>>>(out, upw, upb, y_in, gamma);
}